// Round 7
// baseline (885.579 us; speedup 1.0000x reference)
//
#include <hip/hip_runtime.h>
#include <hip/hip_bf16.h>
#include <math.h>

#define D_MODEL 2048
#define N_LAYERS 2
#define ED 4096
#define D_STATE 16
#define D_CONV 4
#define DT_RANK 128
#define N_HEADS 4
#define HEAD_DIM 512
#define BATCH 4
#define SEQL 256

typedef __bf16 bf16_t;
typedef bf16_t bf16x8 __attribute__((ext_vector_type(8)));
typedef bf16_t bf16x4 __attribute__((ext_vector_type(4)));
typedef float f32x4 __attribute__((ext_vector_type(4)));

// ---------------------------------------------------------------- utilities
__device__ __forceinline__ float warp_reduce_sum(float v) {
#pragma unroll
    for (int off = 1; off < 64; off <<= 1) v += __shfl_xor(v, off);
    return v;
}
__device__ __forceinline__ float warp_reduce_max(float v) {
#pragma unroll
    for (int off = 1; off < 64; off <<= 1) v = fmaxf(v, __shfl_xor(v, off));
    return v;
}

__device__ __forceinline__ void gload_lds16(const bf16_t* g, bf16_t* l) {
    __builtin_amdgcn_global_load_lds(
        (const __attribute__((address_space(1))) unsigned int*)g,
        (__attribute__((address_space(3))) unsigned int*)l, 16, 0, 0);
}

// ---------------------------------------------------------------- copy / convert
__global__ void copy_kernel(const float* __restrict__ src, float* __restrict__ dst, int n) {
    int i = blockIdx.x * blockDim.x + threadIdx.x;
    if (i < n) dst[i] = src[i];
}

__global__ void f2b_kernel(const float* __restrict__ src, bf16_t* __restrict__ dst, int n) {
    int i = blockIdx.x * blockDim.x + threadIdx.x;
    if (i < n) dst[i] = (bf16_t)src[i];
}

__global__ void dt_pack_kernel(const float* __restrict__ dbc, bf16_t* __restrict__ dt) {
    int i = blockIdx.x * blockDim.x + threadIdx.x;  // < 1024*128
    int row = i >> 7, col = i & 127;
    dt[i] = (bf16_t)dbc[row * (DT_RANK + 2 * D_STATE) + col];
}

__global__ void ksum_kernel(const float* __restrict__ part, float* __restrict__ out, int n,
                            int nz, long stride) {
    int i = blockIdx.x * blockDim.x + threadIdx.x;
    if (i >= n) return;
    float s = 0.f;
    for (int z = 0; z < nz; ++z) s += part[(long)z * stride + i];
    out[i] = s;
}

// sum split-K partials and ADD into out (+ optional bias, indexed i & bmask)
__global__ void ksum_add_kernel(const float* __restrict__ part, float* __restrict__ out, int n,
                                int nz, long stride, const float* __restrict__ bias, int bmask) {
    int i = blockIdx.x * blockDim.x + threadIdx.x;
    if (i >= n) return;
    float s = out[i];
    for (int z = 0; z < nz; ++z) s += part[(long)z * stride + i];
    if (bias) s += bias[i & bmask];
    out[i] = s;
}

// ---------------------------------------------------------------- rmsnorm (bf16 out)
__global__ void rmsnorm_kernel(const float* __restrict__ x, const float* __restrict__ w,
                               bf16_t* __restrict__ o) {
    int row = blockIdx.x;
    int tid = threadIdx.x;  // 256
    const float* xr = x + (long)row * D_MODEL;
    float ss = 0.f;
    for (int i = tid; i < D_MODEL; i += 256) { float v = xr[i]; ss += v * v; }
    ss = warp_reduce_sum(ss);
    __shared__ float r[4];
    int wave = tid >> 6;
    if ((tid & 63) == 0) r[wave] = ss;
    __syncthreads();
    float tot = r[0] + r[1] + r[2] + r[3];
    float sc = rsqrtf(tot / (float)D_MODEL + 1e-5f);
    bf16_t* orow = o + (long)row * D_MODEL;
    for (int i = tid; i < D_MODEL; i += 256) orow[i] = (bf16_t)(xr[i] * sc * w[i]);
}

// ---------------------------------------------------------------- bf16 MFMA GEMM (fp32 B weights)
__global__ __launch_bounds__(256, 2) void gemm_bf16(
    const bf16_t* __restrict__ A, int lda, const float* __restrict__ B, int ldb,
    float* __restrict__ C, int ldc, int N, int K_len, const float* __restrict__ bias,
    int accumulate, int out_bf16, long partial_stride) {
    __shared__ bf16_t As[128 * 32];
    __shared__ bf16_t Bs[128 * 32];
    const int tid = threadIdx.x;
    const int lane = tid & 63;
    const int wave = tid >> 6;
    const int m0 = blockIdx.y * 128;
    const int n0 = blockIdx.x * 128;
    const int kbeg = blockIdx.z * K_len;

    const int cA = wave * 2;
    const bf16_t* gA0 = A + (long)(m0 + cA * 16 + (lane >> 2)) * lda + kbeg + (lane & 3) * 8;
    const bf16_t* gA1 = gA0 + 16L * lda;
    bf16_t* lA0 = &As[cA * 512];
    bf16_t* lA1 = &As[cA * 512 + 512];

    const int brow = tid >> 1;
    const int bcol = (tid & 1) * 16;
    const bool bvalid = (n0 + brow) < N;
    const float* gB = B + (long)(n0 + brow) * ldb + kbeg + bcol;
    bf16_t* lB = &Bs[brow * 32 + bcol];

    const int wr = wave >> 1, wc = wave & 1;
    const int fr = lane & 15, fq = lane >> 4;
    const bf16_t* aBase = &As[(wr * 64 + fr) * 32 + fq * 8];
    const bf16_t* bBase = &Bs[(wc * 64 + fr) * 32 + fq * 8];

    f32x4 acc[4][4] = {};

    for (int kk = 0; kk < K_len; kk += 32) {
        gload_lds16(gA0, lA0);
        gload_lds16(gA1, lA1);
        gA0 += 32;
        gA1 += 32;
        if (bvalid) {
            float4 v0 = *(const float4*)(gB);
            float4 v1 = *(const float4*)(gB + 4);
            float4 v2 = *(const float4*)(gB + 8);
            float4 v3 = *(const float4*)(gB + 12);
            gB += 32;
            bf16x8 p0, p1;
            p0[0] = (bf16_t)v0.x; p0[1] = (bf16_t)v0.y; p0[2] = (bf16_t)v0.z; p0[3] = (bf16_t)v0.w;
            p0[4] = (bf16_t)v1.x; p0[5] = (bf16_t)v1.y; p0[6] = (bf16_t)v1.z; p0[7] = (bf16_t)v1.w;
            p1[0] = (bf16_t)v2.x; p1[1] = (bf16_t)v2.y; p1[2] = (bf16_t)v2.z; p1[3] = (bf16_t)v2.w;
            p1[4] = (bf16_t)v3.x; p1[5] = (bf16_t)v3.y; p1[6] = (bf16_t)v3.z; p1[7] = (bf16_t)v3.w;
            *(bf16x8*)lB = p0;
            *((bf16x8*)lB + 1) = p1;
        }
        __syncthreads();
        bf16x8 af[4], bfr[4];
#pragma unroll
        for (int m = 0; m < 4; ++m) af[m] = *(const bf16x8*)(aBase + m * 512);
#pragma unroll
        for (int n = 0; n < 4; ++n) bfr[n] = *(const bf16x8*)(bBase + n * 512);
#pragma unroll
        for (int m = 0; m < 4; ++m)
#pragma unroll
            for (int n = 0; n < 4; ++n)
                acc[m][n] = __builtin_amdgcn_mfma_f32_16x16x32_bf16(af[m], bfr[n], acc[m][n], 0, 0, 0);
        __syncthreads();
    }

    float* Cz = C + ((gridDim.z > 1) ? (long)blockIdx.z * partial_stride : 0L);
#pragma unroll
    for (int m = 0; m < 4; ++m) {
        const int grow0 = m0 + wr * 64 + m * 16 + fq * 4;
#pragma unroll
        for (int n = 0; n < 4; ++n) {
            const int gcol = n0 + wc * 64 + n * 16 + fr;
            if (gcol >= N) continue;
            float bv = bias ? bias[gcol] : 0.f;
#pragma unroll
            for (int r = 0; r < 4; ++r) {
                long idx = (long)(grow0 + r) * ldc + gcol;
                float v = acc[m][n][r] + bv;
                if (out_bf16) {
                    ((bf16_t*)Cz)[idx] = (bf16_t)v;
                } else {
                    if (accumulate) v += Cz[idx];
                    Cz[idx] = v;
                }
            }
        }
    }
}

// ---------------------------------------------------------------- bf16xbf16 batched MFMA GEMM
__global__ __launch_bounds__(256, 2) void gemm_bb(
    const bf16_t* __restrict__ A, long aO, long aI, int lda,
    const bf16_t* __restrict__ B, long bO, long bI, int ldb,
    void* __restrict__ Cv, long cO, long cI, int ldc,
    int K_len, int out_bf16) {
    __shared__ bf16_t As[128 * 32];
    __shared__ bf16_t Bs[128 * 32];
    const int tid = threadIdx.x;
    const int lane = tid & 63;
    const int wave = tid >> 6;
    const int z = blockIdx.z, zb = z >> 2, zh = z & 3;
    const bf16_t* Az = A + (long)zb * aO + (long)zh * aI;
    const bf16_t* Bz = B + (long)zb * bO + (long)zh * bI;
    const int m0 = blockIdx.y * 128;
    const int n0 = blockIdx.x * 128;

    const int cA = wave * 2;
    const bf16_t* gA0 = Az + (long)(m0 + cA * 16 + (lane >> 2)) * lda + (lane & 3) * 8;
    const bf16_t* gA1 = gA0 + 16L * lda;
    const bf16_t* gB0 = Bz + (long)(n0 + cA * 16 + (lane >> 2)) * ldb + (lane & 3) * 8;
    const bf16_t* gB1 = gB0 + 16L * ldb;
    bf16_t* lA0 = &As[cA * 512];
    bf16_t* lA1 = lA0 + 512;
    bf16_t* lB0 = &Bs[cA * 512];
    bf16_t* lB1 = lB0 + 512;

    const int wr = wave >> 1, wc = wave & 1;
    const int fr = lane & 15, fq = lane >> 4;
    const bf16_t* aBase = &As[(wr * 64 + fr) * 32 + fq * 8];
    const bf16_t* bBase = &Bs[(wc * 64 + fr) * 32 + fq * 8];

    f32x4 acc[4][4] = {};

    for (int kk = 0; kk < K_len; kk += 32) {
        gload_lds16(gA0, lA0);
        gload_lds16(gA1, lA1);
        gload_lds16(gB0, lB0);
        gload_lds16(gB1, lB1);
        gA0 += 32; gA1 += 32; gB0 += 32; gB1 += 32;
        __syncthreads();
        bf16x8 af[4], bfr[4];
#pragma unroll
        for (int m = 0; m < 4; ++m) af[m] = *(const bf16x8*)(aBase + m * 512);
#pragma unroll
        for (int n = 0; n < 4; ++n) bfr[n] = *(const bf16x8*)(bBase + n * 512);
#pragma unroll
        for (int m = 0; m < 4; ++m)
#pragma unroll
            for (int n = 0; n < 4; ++n)
                acc[m][n] = __builtin_amdgcn_mfma_f32_16x16x32_bf16(af[m], bfr[n], acc[m][n], 0, 0, 0);
        __syncthreads();
    }

#pragma unroll
    for (int m = 0; m < 4; ++m) {
        const int grow0 = m0 + wr * 64 + m * 16 + fq * 4;
#pragma unroll
        for (int n = 0; n < 4; ++n) {
            const int gcol = n0 + wc * 64 + n * 16 + fr;
#pragma unroll
            for (int r = 0; r < 4; ++r) {
                long idx = (long)(grow0 + r) * ldc + gcol;
                if (out_bf16) {
                    bf16_t* Cb = (bf16_t*)Cv + (long)zb * cO + (long)zh * cI;
                    Cb[idx] = (bf16_t)acc[m][n][r];
                } else {
                    float* Cf = (float*)Cv + (long)zb * cO + (long)zh * cI;
                    Cf[idx] = acc[m][n][r];
                }
            }
        }
    }
}

// ---------------------------------------------------------------- V transpose (attention)
__global__ void vtrans_kernel(const bf16_t* __restrict__ qkvb, bf16_t* __restrict__ vt) {
    int z = blockIdx.z;  // b*4+h
    int b = z >> 2, h = z & 3;
    int d0 = blockIdx.x * 64, k0 = blockIdx.y * 64;
    __shared__ bf16_t tile[64][72];
    int t = threadIdx.x;  // 256
    int r = t >> 2;
    int c4 = (t & 3) * 16;
    const bf16_t* src = qkvb + ((long)(b * SEQL + k0 + r)) * (3 * D_MODEL) + 2 * D_MODEL +
                        h * HEAD_DIM + d0 + c4;
    bf16x8 v0 = *(const bf16x8*)src;
    bf16x8 v1 = *(const bf16x8*)(src + 8);
#pragma unroll
    for (int j = 0; j < 8; ++j) tile[r][c4 + j] = v0[j];
#pragma unroll
    for (int j = 0; j < 8; ++j) tile[r][c4 + 8 + j] = v1[j];
    __syncthreads();
    int dd = t >> 2, kc = (t & 3) * 16;
    bf16_t* dst = vt + (long)z * (HEAD_DIM * SEQL) + (long)(d0 + dd) * SEQL + k0 + kc;
    bf16x8 o0, o1;
#pragma unroll
    for (int j = 0; j < 8; ++j) o0[j] = tile[kc + j][dd];
#pragma unroll
    for (int j = 0; j < 8; ++j) o1[j] = tile[kc + 8 + j][dd];
    *(bf16x8*)dst = o0;
    *(bf16x8*)(dst + 8) = o1;
}

// ---------------------------------------------------------------- softmax rows of S
__global__ void softmax_kernel(const float* __restrict__ S, bf16_t* __restrict__ P) {
    long row = blockIdx.x;  // 4096 = (b,h,q)
    int tid = threadIdx.x;  // 256
    float s = S[row * SEQL + tid] * 0.044194173824159216f;  // 1/sqrt(512)
    __shared__ float red[4];
    float m = warp_reduce_max(s);
    if ((tid & 63) == 0) red[tid >> 6] = m;
    __syncthreads();
    float gm = fmaxf(fmaxf(red[0], red[1]), fmaxf(red[2], red[3]));
    __syncthreads();
    float p = __expf(s - gm);
    float su = warp_reduce_sum(p);
    if ((tid & 63) == 0) red[tid >> 6] = su;
    __syncthreads();
    float gs = red[0] + red[1] + red[2] + red[3];
    P[row * SEQL + tid] = (bf16_t)(p / gs);
}

// ---------------------------------------------------------------- conv + silu + transpose
__global__ void conv_tr_kernel(const bf16_t* __restrict__ xzb, const float* __restrict__ cw,
                               const float* __restrict__ cb, bf16_t* __restrict__ xT,
                               bf16_t* __restrict__ xcb, bf16_t* __restrict__ zT) {
    __shared__ bf16_t xin[68][64];
    __shared__ bf16_t outt[64][72];  // [e_local][l_local]
    const int e0 = blockIdx.x * 64, l0 = blockIdx.y * 64, b = blockIdx.z;
    const int t = threadIdx.x;
    const int r = t >> 4;            // 0..15
    const int c = (t & 15) * 4;      // 0..60

#pragma unroll
    for (int i = 0; i < 5; ++i) {
        int m = r + i * 16;
        if (m < 67) {
            int l = l0 - 3 + m;
            bf16x4 v;
            if (l >= 0)
                v = *(const bf16x4*)(xzb + ((long)(b * SEQL + l)) * (2 * ED) + e0 + c);
            else {
                v[0] = (bf16_t)0.f; v[1] = (bf16_t)0.f; v[2] = (bf16_t)0.f; v[3] = (bf16_t)0.f;
            }
            *(bf16x4*)&xin[m][c] = v;
        }
    }
    __syncthreads();

    {
        const int e_l = t & 63;
        const int lbase = (t >> 6) * 16;
        const float4 wv = *(const float4*)(cw + (long)(e0 + e_l) * 4);
        const float bias = cb[e0 + e_l];
#pragma unroll
        for (int k = 0; k < 16; ++k) {
            int l = lbase + k;
            float acc = bias + wv.x * (float)xin[l][e_l] + wv.y * (float)xin[l + 1][e_l] +
                        wv.z * (float)xin[l + 2][e_l] + wv.w * (float)xin[l + 3][e_l];
            float s = acc / (1.f + __expf(-acc));
            outt[e_l][l] = (bf16_t)s;
        }
    }
    __syncthreads();

    {
        int er = t >> 2, lc = (t & 3) * 16;
        bf16x8 a = *(bf16x8*)&outt[er][lc];
        bf16x8 bb8 = *(bf16x8*)&outt[er][lc + 8];
        bf16_t* dst = xT + ((long)b * ED + e0 + er) * SEQL + l0 + lc;
        *(bf16x8*)dst = a;
        *(bf16x8*)(dst + 8) = bb8;
    }
    {
        int lr = t >> 2, ec = (t & 3) * 16;
        bf16_t tmp[16];
#pragma unroll
        for (int j = 0; j < 16; ++j) tmp[j] = outt[ec + j][lr];
        bf16_t* dst = xcb + ((long)(b * SEQL + l0 + lr)) * ED + e0 + ec;
        *(bf16x8*)dst = *(bf16x8*)&tmp[0];
        *(bf16x8*)(dst + 8) = *(bf16x8*)&tmp[8];
    }
    __syncthreads();

#pragma unroll
    for (int i = 0; i < 4; ++i) {
        int m = r + i * 16;
        bf16x4 v = *(const bf16x4*)(xzb + ((long)(b * SEQL + l0 + m)) * (2 * ED) + ED + e0 + c);
        *(bf16x4*)&xin[m][c] = v;
    }
    __syncthreads();
    {
        int er = t >> 2, lc = (t & 3) * 16;
        bf16_t tz[16];
#pragma unroll
        for (int j = 0; j < 16; ++j) tz[j] = xin[lc + j][er];
        bf16_t* dst = zT + ((long)b * ED + e0 + er) * SEQL + l0 + lc;
        *(bf16x8*)dst = *(bf16x8*)&tz[0];
        *(bf16x8*)(dst + 8) = *(bf16x8*)&tz[8];
    }
}

// ---------------------------------------------------------------- softplus + transpose
__global__ void softplus_tr_kernel(const float* __restrict__ delta, const float* __restrict__ dt_b,
                                   float* __restrict__ dT) {
    __shared__ float tile[64][65];
    const int e0 = blockIdx.x * 64, l0 = blockIdx.y * 64, b = blockIdx.z;
    const int t = threadIdx.x;
    const int r = t >> 4, c = (t & 15) * 4;
#pragma unroll
    for (int i = 0; i < 4; ++i) {
        int l = r + i * 16;
        float4 v = *(const float4*)(delta + ((long)(b * SEQL + l0 + l)) * ED + e0 + c);
        float4 bb = *(const float4*)(dt_b + e0 + c);
        float u0 = v.x + bb.x, u1 = v.y + bb.y, u2 = v.z + bb.z, u3 = v.w + bb.w;
        tile[l][c] = (u0 > 20.f) ? u0 : log1pf(__expf(u0));
        tile[l][c + 1] = (u1 > 20.f) ? u1 : log1pf(__expf(u1));
        tile[l][c + 2] = (u2 > 20.f) ? u2 : log1pf(__expf(u2));
        tile[l][c + 3] = (u3 > 20.f) ? u3 : log1pf(__expf(u3));
    }
    __syncthreads();
#pragma unroll
    for (int i = 0; i < 4; ++i) {
        int ee = r + i * 16;
        float4 w;
        w.x = tile[c][ee];
        w.y = tile[c + 1][ee];
        w.z = tile[c + 2][ee];
        w.w = tile[c + 3][ee];
        *(float4*)(dT + ((long)b * ED + e0 + ee) * SEQL + l0 + c) = w;
    }
}

// ---------------------------------------------------------------- chunk-parallel selective scan
// lane owns (e, chunk): 16 chunks of 16 steps; B/C staged in LDS (padded rows).
// grid = (ED/16, B); block = 256.
__global__ __launch_bounds__(256) void scan_chunk_kernel(
    const float* __restrict__ dT, const bf16_t* __restrict__ xT, const bf16_t* __restrict__ zT,
    const float* __restrict__ dbc, const float* __restrict__ A_log, const float* __restrict__ Dp,
    bf16_t* __restrict__ yT) {
    __shared__ float bc[SEQL][36];  // cols 0..15 = B, 16..31 = C; pad to 36 (2-way bank alias max)
    const int t = threadIdx.x;
    const int chunk = t & 15;
    const int el = t >> 4;
    const int b = blockIdx.y;
    const int e = blockIdx.x * 16 + el;
    const int l0 = chunk * 16;
    const int R = DT_RANK + 2 * D_STATE;  // 160

    // ---- stage dbc B/C columns into LDS (coalesced: 8 threads x float4 per row)
    {
        const int row0 = t >> 3;
        const int col = (t & 7) * 4;
        const float* src = dbc + (long)b * SEQL * R + DT_RANK;
#pragma unroll
        for (int it = 0; it < 8; ++it) {
            int row = row0 + it * 32;
            *(float4*)&bc[row][col] = *(const float4*)(src + (long)row * R + col);
        }
    }

    float Ar[16];
    {
        const float* ap = A_log + (long)e * D_STATE;
#pragma unroll
        for (int n = 0; n < 16; n += 4) {
            float4 v = *(const float4*)(ap + n);
            Ar[n] = -__expf(v.x);
            Ar[n + 1] = -__expf(v.y);
            Ar[n + 2] = -__expf(v.z);
            Ar[n + 3] = -__expf(v.w);
        }
    }
    float d[16];
    {
        const float* dp = dT + ((long)b * ED + e) * SEQL + l0;
#pragma unroll
        for (int j = 0; j < 16; j += 4) *(float4*)&d[j] = *(const float4*)(dp + j);
    }
    float xf[16];
    {
        const bf16_t* xp = xT + ((long)b * ED + e) * SEQL + l0;
        bf16x8 x0 = *(const bf16x8*)xp;
        bf16x8 x1 = *(const bf16x8*)(xp + 8);
#pragma unroll
        for (int j = 0; j < 8; ++j) {
            xf[j] = (float)x0[j];
            xf[8 + j] = (float)x1[j];
        }
    }
    __syncthreads();

    float P[16], S[16];
#pragma unroll
    for (int n = 0; n < 16; ++n) {
        P[n] = 1.f;
        S[n] = 0.f;
    }

    // pass A: per-chunk summary from h=0 (B from LDS)
#pragma unroll
    for (int j = 0; j < 16; ++j) {
        const float* br = &bc[l0 + j][0];
        float dj = d[j];
        float dx = dj * xf[j];
#pragma unroll
        for (int n = 0; n < 16; ++n) {
            float dA = __expf(dj * Ar[n]);
            S[n] = dA * S[n] + dx * br[n];
            P[n] *= dA;
        }
    }

    // combine: inclusive scan over 16 chunk-lanes
#pragma unroll
    for (int off = 1; off < 16; off <<= 1) {
        float Pp[16], Sp[16];
#pragma unroll
        for (int n = 0; n < 16; ++n) {
            Pp[n] = __shfl_up(P[n], off, 16);
            Sp[n] = __shfl_up(S[n], off, 16);
        }
        if (chunk >= off) {
#pragma unroll
            for (int n = 0; n < 16; ++n) {
                S[n] = P[n] * Sp[n] + S[n];
                P[n] *= Pp[n];
            }
        }
    }

    // exclusive: h_init[chunk] = inclusive_S[chunk-1]
    float h[16];
#pragma unroll
    for (int n = 0; n < 16; ++n) {
        float hs = __shfl_up(S[n], 1, 16);
        h[n] = (chunk == 0) ? 0.f : hs;
    }

    const float dpe = Dp[e];
    float zf[16];
    {
        const bf16_t* zp = zT + ((long)b * ED + e) * SEQL + l0;
        bf16x8 z0 = *(const bf16x8*)zp;
        bf16x8 z1 = *(const bf16x8*)(zp + 8);
#pragma unroll
        for (int j = 0; j < 8; ++j) {
            zf[j] = (float)z0[j];
            zf[8 + j] = (float)z1[j];
        }
    }

    bf16_t yv[16];
    // pass C: replay with true h_init (B,C from LDS)
#pragma unroll
    for (int j = 0; j < 16; ++j) {
        const float* br = &bc[l0 + j][0];
        float dj = d[j];
        float dx = dj * xf[j];
        float y = 0.f;
#pragma unroll
        for (int n = 0; n < 16; ++n) {
            float dA = __expf(dj * Ar[n]);
            h[n] = dA * h[n] + dx * br[n];
            y += h[n] * br[16 + n];
        }
        y += xf[j] * dpe;
        float z = zf[j];
        y *= z / (1.f + __expf(-z));
        yv[j] = (bf16_t)y;
    }
    bf16_t* yp = yT + ((long)b * ED + e) * SEQL + l0;
    *(bf16x8*)yp = *(bf16x8*)&yv[0];
    *(bf16x8*)(yp + 8) = *(bf16x8*)&yv[8];
}

// ---------------------------------------------------------------- yT [B][ED][L] -> Y [B*L][ED]
__global__ void ytr_kernel(const bf16_t* __restrict__ yT, bf16_t* __restrict__ Y) {
    __shared__ bf16_t tl[64][72];
    const int e0 = blockIdx.x * 64, l0 = blockIdx.y * 64, b = blockIdx.z;
    const int t = threadIdx.x;
    {
        int er = t >> 2, lc = (t & 3) * 16;
        const bf16_t* src = yT + ((long)b * ED + e0 + er) * SEQL + l0 + lc;
        bf16x8 a = *(const bf16x8*)src;
        bf16x8 bb8 = *(const bf16x8*)(src + 8);
        *(bf16x8*)&tl[er][lc] = a;
        *(bf16x8*)&tl[er][lc + 8] = bb8;
    }
    __syncthreads();
    {
        int lr = t >> 2, ec = (t & 3) * 16;
        bf16_t tmp[16];
#pragma unroll
        for (int j = 0; j < 16; ++j) tmp[j] = tl[ec + j][lr];
        bf16_t* dst = Y + ((long)(b * SEQL + l0 + lr)) * ED + e0 + ec;
        *(bf16x8*)dst = *(bf16x8*)&tmp[0];
        *(bf16x8*)(dst + 8) = *(bf16x8*)&tmp[8];
    }
}

// ---------------------------------------------------------------- head GEMV1
__global__ void head_gemv1(const float* __restrict__ H, const float* __restrict__ w1,
                           const float* __restrict__ b1, float* __restrict__ hm1) {
    int b = blockIdx.y;
    int wave = threadIdx.x >> 6, lane = threadIdx.x & 63;
    int n = blockIdx.x * 4 + wave;
    const float* last = H + ((long)(b * SEQL + SEQL - 1)) * D_MODEL;
    const float* wr = w1 + (long)n * D_MODEL;
    float s = 0.f;
    for (int j = lane * 4; j < D_MODEL; j += 256) {
        float4 a = *(const float4*)(last + j);
        float4 w = *(const float4*)(wr + j);
        s += a.x * w.x + a.y * w.y + a.z * w.z + a.w * w.w;
    }
    s = warp_reduce_sum(s);
    if (lane == 0) hm1[b * 1024 + n] = s + b1[n];
}

// ---------------------------------------------------------------- head final
__global__ void head_final(const float* __restrict__ hm1, const float* __restrict__ ln_g,
                           const float* __restrict__ ln_b, const float* __restrict__ w2,
                           const float* __restrict__ b2, float* __restrict__ out) {
    int b = blockIdx.x;
    int tid = threadIdx.x;  // 1024
    __shared__ float hm[1024];
    __shared__ float r1[16], r2[16];
    __shared__ float stats[2];
    __shared__ float outs[64];

    float v = hm1[b * 1024 + tid];
    float s1 = warp_reduce_sum(v);
    float s2 = warp_reduce_sum(v * v);
    int wave = tid >> 6;
    if ((tid & 63) == 0) { r1[wave] = s1; r2[wave] = s2; }
    __syncthreads();
    if (tid == 0) {
        float t1 = 0.f, t2 = 0.f;
        for (int w = 0; w < 16; ++w) { t1 += r1[w]; t2 += r2[w]; }
        float mean = t1 / 1024.f;
        stats[0] = mean;
        stats[1] = rsqrtf(t2 / 1024.f - mean * mean + 1e-5f);
    }
    __syncthreads();
    float x = (v - stats[0]) * stats[1] * ln_g[tid] + ln_b[tid];
    x = (x > 0.f) ? x : (__expf(x) - 1.f);
    hm[tid] = x;
    __syncthreads();

    int o = tid >> 4, kk = tid & 15;
    float a = 0.f;
    const float* w2r = w2 + (long)o * 1024;
    for (int j = kk; j < 1024; j += 16) a += hm[j] * w2r[j];
#pragma unroll
    for (int off = 1; off < 16; off <<= 1) a += __shfl_xor(a, off);
    if (kk == 0) outs[o] = a + b2[o];
    __syncthreads();
    if (tid < 64) {
        float vv = outs[tid];
        float ss = warp_reduce_sum(vv * vv);
        out[b * 64 + tid] = vv / fmaxf(sqrtf(ss), 1e-12f);
    }
}

// ---------------------------------------------------------------- launch
extern "C" void kernel_launch(void* const* d_in, const int* in_sizes, int n_in,
                              void* d_out, int out_size, void* d_ws, size_t ws_size,
                              hipStream_t stream) {
    const float* x = (const float*)d_in[0];
    const float* norm_w = (const float*)d_in[1];
    const float* in_proj_w = (const float*)d_in[2];
    const float* conv_w = (const float*)d_in[3];
    const float* conv_b = (const float*)d_in[4];
    const float* x_proj_w = (const float*)d_in[5];
    const float* dt_proj_w = (const float*)d_in[6];
    const float* dt_proj_b = (const float*)d_in[7];
    const float* A_log = (const float*)d_in[8];
    const float* D_param = (const float*)d_in[9];
    const float* out_proj_w = (const float*)d_in[10];
    const float* attn_in_w = (const float*)d_in[11];
    const float* attn_in_b = (const float*)d_in[12];
    const float* attn_out_w = (const float*)d_in[13];
    const float* attn_out_b = (const float*)d_in[14];
    const float* w1 = (const float*)d_in[15];
    const float* b1 = (const float*)d_in[16];
    const float* ln_g = (const float*)d_in[17];
    const float* ln_b = (const float*)d_in[18];
    const float* w2 = (const float*)d_in[19];
    const float* b2 = (const float*)d_in[20];

    float* ws = (float*)d_ws;
    size_t o = 0;
    float* H = ws + o;      o += 2097152;       // (B,L,D) fp32
    float* SCR = ws + o;    o += 6291456;       // XZb/dT/yT (mamba) | QKV etc (attn) | splitK partials
    float* DELTA = ws + o;  o += 4194304;       // (B,L,ED) fp32  (contiguous after SCR)
    float* DBC = ws + o;    o += 163840;        // (B,L,160) fp32
    float* XPART = ws + o;  o += 1310720;       // 8 x (1024,160) split-K partials
    bf16_t* XNb = (bf16_t*)(ws + o);  o += 1048576;  // (B,L,D) bf16
    bf16_t* XCb = (bf16_t*)(ws + o);  o += 2097152;  // (B,L,ED) bf16
    bf16_t* DTb = (bf16_t*)(ws + o);  o += 65536;    // (1024,128) bf16
    bf16_t* Yb = (bf16_t*)(ws + o);   o += 2097152;  // (B,L,ED) bf16
    bf16_t* Hb = (bf16_t*)(ws + o);   o += 1048576;  // (B,L,D) bf16
    bf16_t* AOb = (bf16_t*)(ws + o);  o += 1048576;  // (B,L,D) bf16
    float* HM1 = ws + o;    o += 4096;          // (B,1024) fp32
    bf16_t* XT = (bf16_t*)(ws + o);   o += 2097152;  // [B][ED][L] bf16
    bf16_t* ZT = (bf16_t*)(ws + o);   o += 2097152;  // [B][ED][L] bf16

    bf16_t* XZb = (bf16_t*)SCR;                       // [B*L][2ED] bf16 (dead after conv_tr)
    float* DTT = SCR;                                 // [B][ED][L] f32 (aliases XZb; written after)
    bf16_t* YTT = (bf16_t*)(SCR + 4194304);           // [B][ED][L] bf16
    float* PART = SCR;                                // splitK partials (SCR+DELTA contiguous)

    bf16_t* QKVb = (bf16_t*)SCR;                      // attention phase
    float* SBUF = SCR + 3145728;
    bf16_t* Pb = (bf16_t*)(SCR + 3145728 + 1048576);
    bf16_t* VTb = (bf16_t*)(SCR + 3145728 + 1048576 + 524288);

    const int M = BATCH * SEQL;  // 1024
    const long S_H = (long)M * D_MODEL;

    copy_kernel<<<(S_H + 255) / 256, 256, 0, stream>>>(x, H, (int)S_H);

    for (int i = 0; i < N_LAYERS; ++i) {
        rmsnorm_kernel<<<M, 256, 0, stream>>>(H, norm_w + (long)i * D_MODEL, XNb);
        gemm_bf16<<<dim3(64, 8, 1), 256, 0, stream>>>(
            XNb, D_MODEL, in_proj_w + (long)i * 2 * ED * D_MODEL, D_MODEL, (float*)XZb, 2 * ED,
            2 * ED, D_MODEL, nullptr, 0, 1, 0);
        conv_tr_kernel<<<dim3(64, 4, 4), 256, 0, stream>>>(
            XZb, conv_w + (long)i * ED * D_CONV, conv_b + (long)i * ED, XT, XCb, ZT);
        gemm_bf16<<<dim3(2, 8, 8), 256, 0, stream>>>(
            XCb, ED, x_proj_w + (long)i * (DT_RANK + 2 * D_STATE) * ED, ED, XPART,
            DT_RANK + 2 * D_STATE, DT_RANK + 2 * D_STATE, ED / 8, nullptr, 0, 0,
            (long)M * (DT_RANK + 2 * D_STATE));
        ksum_kernel<<<640, 256, 0, stream>>>(XPART, DBC, M * (DT_RANK + 2 * D_STATE), 8,
                                             (long)M * (DT_RANK + 2 * D_STATE));
        dt_pack_kernel<<<512, 256, 0, stream>>>(DBC, DTb);
        gemm_bf16<<<dim3(32, 8, 1), 256, 0, stream>>>(
            DTb, DT_RANK, dt_proj_w + (long)i * ED * DT_RANK, DT_RANK, DELTA, ED, ED, DT_RANK,
            nullptr, 0, 0, 0);
        softplus_tr_kernel<<<dim3(64, 4, 4), 256, 0, stream>>>(DELTA, dt_proj_b + (long)i * ED,
                                                               DTT);
        scan_chunk_kernel<<<dim3(ED / 16, BATCH), 256, 0, stream>>>(
            DTT, XT, ZT, DBC, A_log + (long)i * ED * D_STATE, D_param + (long)i * ED, YTT);
        ytr_kernel<<<dim3(64, 4, 4), 256, 0, stream>>>(YTT, Yb);
        // out_proj: split-K=4 (512 blocks) -> fp32 partials over dead SCR/DELTA, then add into H
        gemm_bf16<<<dim3(16, 8, 4), 256, 0, stream>>>(
            Yb, ED, out_proj_w + (long)i * D_MODEL * ED, ED, PART, D_MODEL, D_MODEL, ED / 4,
            nullptr, 0, 0, (long)M * D_MODEL);
        ksum_add_kernel<<<8192, 256, 0, stream>>>(PART, H, M * D_MODEL, 4, (long)M * D_MODEL,
                                                  nullptr, 0);
    }

    f2b_kernel<<<(int)((S_H + 255) / 256), 256, 0, stream>>>(H, Hb, (int)S_H);
    gemm_bf16<<<dim3(48, 8, 1), 256, 0, stream>>>(Hb, D_MODEL, attn_in_w, D_MODEL, (float*)QKVb,
                                                  3 * D_MODEL, 3 * D_MODEL, D_MODEL, attn_in_b, 0,
                                                  1, 0);
    vtrans_kernel<<<dim3(8, 4, 16), 256, 0, stream>>>(QKVb, VTb);
    gemm_bb<<<dim3(2, 2, 16), 256, 0, stream>>>(
        QKVb, (long)SEQL * 3 * D_MODEL, HEAD_DIM, 3 * D_MODEL,
        QKVb + D_MODEL, (long)SEQL * 3 * D_MODEL, HEAD_DIM, 3 * D_MODEL,
        SBUF, 4L * SEQL * SEQL, (long)SEQL * SEQL, SEQL, HEAD_DIM, 0);
    softmax_kernel<<<BATCH * N_HEADS * SEQL, 256, 0, stream>>>(SBUF, Pb);
    gemm_bb<<<dim3(4, 2, 16), 256, 0, stream>>>(
        Pb, 4L * SEQL * SEQL, (long)SEQL * SEQL, SEQL,
        VTb, 4L * HEAD_DIM * SEQL, (long)HEAD_DIM * SEQL, SEQL,
        AOb, (long)SEQL * D_MODEL, HEAD_DIM, D_MODEL, SEQL, 1);
    // attn_out: split-K=4 (512 blocks); bias folded into the reduce (added once)
    gemm_bf16<<<dim3(16, 8, 4), 256, 0, stream>>>(
        AOb, D_MODEL, attn_out_w, D_MODEL, PART, D_MODEL, D_MODEL, D_MODEL / 4, nullptr, 0, 0,
        (long)M * D_MODEL);
    ksum_add_kernel<<<8192, 256, 0, stream>>>(PART, H, M * D_MODEL, 4, (long)M * D_MODEL,
                                              attn_out_b, D_MODEL - 1);

    head_gemv1<<<dim3(256, 4), 256, 0, stream>>>(H, w1, b1, HM1);
    head_final<<<BATCH, 1024, 0, stream>>>(HM1, ln_g, ln_b, w2, b2, (float*)d_out);
}

// Round 8
// 769.504 us; speedup vs baseline: 1.1508x; 1.1508x over previous
//
#include <hip/hip_runtime.h>
#include <hip/hip_bf16.h>
#include <math.h>

#define D_MODEL 2048
#define N_LAYERS 2
#define ED 4096
#define D_STATE 16
#define D_CONV 4
#define DT_RANK 128
#define N_HEADS 4
#define HEAD_DIM 512
#define BATCH 4
#define SEQL 256

typedef __bf16 bf16_t;
typedef bf16_t bf16x8 __attribute__((ext_vector_type(8)));
typedef bf16_t bf16x4 __attribute__((ext_vector_type(4)));
typedef float f32x4 __attribute__((ext_vector_type(4)));

// ---------------------------------------------------------------- utilities
__device__ __forceinline__ float warp_reduce_sum(float v) {
#pragma unroll
    for (int off = 1; off < 64; off <<= 1) v += __shfl_xor(v, off);
    return v;
}
__device__ __forceinline__ float warp_reduce_max(float v) {
#pragma unroll
    for (int off = 1; off < 64; off <<= 1) v = fmaxf(v, __shfl_xor(v, off));
    return v;
}

__device__ __forceinline__ void gload_lds16(const bf16_t* g, bf16_t* l) {
    __builtin_amdgcn_global_load_lds(
        (const __attribute__((address_space(1))) unsigned int*)g,
        (__attribute__((address_space(3))) unsigned int*)l, 16, 0, 0);
}

// ---------------------------------------------------------------- copy / convert
__global__ void copy_kernel(const float* __restrict__ src, float* __restrict__ dst, int n) {
    int i = blockIdx.x * blockDim.x + threadIdx.x;
    if (i < n) dst[i] = src[i];
}

__global__ void f2b_kernel(const float* __restrict__ src, bf16_t* __restrict__ dst, int n) {
    int i = blockIdx.x * blockDim.x + threadIdx.x;
    if (i < n) dst[i] = (bf16_t)src[i];
}

__global__ void dt_pack_kernel(const float* __restrict__ dbc, bf16_t* __restrict__ dt) {
    int i = blockIdx.x * blockDim.x + threadIdx.x;  // < 1024*128
    int row = i >> 7, col = i & 127;
    dt[i] = (bf16_t)dbc[row * (DT_RANK + 2 * D_STATE) + col];
}

__global__ void ksum_kernel(const float* __restrict__ part, float* __restrict__ out, int n,
                            int nz, long stride) {
    int i = blockIdx.x * blockDim.x + threadIdx.x;
    if (i >= n) return;
    float s = 0.f;
    for (int z = 0; z < nz; ++z) s += part[(long)z * stride + i];
    out[i] = s;
}

// sum split-K partials and ADD into out (+ optional bias, indexed i & bmask)
__global__ void ksum_add_kernel(const float* __restrict__ part, float* __restrict__ out, int n,
                                int nz, long stride, const float* __restrict__ bias, int bmask) {
    int i = blockIdx.x * blockDim.x + threadIdx.x;
    if (i >= n) return;
    float s = out[i];
    for (int z = 0; z < nz; ++z) s += part[(long)z * stride + i];
    if (bias) s += bias[i & bmask];
    out[i] = s;
}

// ---------------------------------------------------------------- rmsnorm (bf16 out)
__global__ void rmsnorm_kernel(const float* __restrict__ x, const float* __restrict__ w,
                               bf16_t* __restrict__ o) {
    int row = blockIdx.x;
    int tid = threadIdx.x;  // 256
    const float* xr = x + (long)row * D_MODEL;
    float ss = 0.f;
    for (int i = tid; i < D_MODEL; i += 256) { float v = xr[i]; ss += v * v; }
    ss = warp_reduce_sum(ss);
    __shared__ float r[4];
    int wave = tid >> 6;
    if ((tid & 63) == 0) r[wave] = ss;
    __syncthreads();
    float tot = r[0] + r[1] + r[2] + r[3];
    float sc = rsqrtf(tot / (float)D_MODEL + 1e-5f);
    bf16_t* orow = o + (long)row * D_MODEL;
    for (int i = tid; i < D_MODEL; i += 256) orow[i] = (bf16_t)(xr[i] * sc * w[i]);
}

// ---------------------------------------------------------------- bf16 MFMA GEMM (fp32 B weights)
__global__ __launch_bounds__(256, 2) void gemm_bf16(
    const bf16_t* __restrict__ A, int lda, const float* __restrict__ B, int ldb,
    float* __restrict__ C, int ldc, int N, int K_len, const float* __restrict__ bias,
    int accumulate, int out_bf16, long partial_stride) {
    __shared__ bf16_t As[128 * 32];
    __shared__ bf16_t Bs[128 * 32];
    const int tid = threadIdx.x;
    const int lane = tid & 63;
    const int wave = tid >> 6;
    const int m0 = blockIdx.y * 128;
    const int n0 = blockIdx.x * 128;
    const int kbeg = blockIdx.z * K_len;

    const int cA = wave * 2;
    const bf16_t* gA0 = A + (long)(m0 + cA * 16 + (lane >> 2)) * lda + kbeg + (lane & 3) * 8;
    const bf16_t* gA1 = gA0 + 16L * lda;
    bf16_t* lA0 = &As[cA * 512];
    bf16_t* lA1 = &As[cA * 512 + 512];

    const int brow = tid >> 1;
    const int bcol = (tid & 1) * 16;
    const bool bvalid = (n0 + brow) < N;
    const float* gB = B + (long)(n0 + brow) * ldb + kbeg + bcol;
    bf16_t* lB = &Bs[brow * 32 + bcol];

    const int wr = wave >> 1, wc = wave & 1;
    const int fr = lane & 15, fq = lane >> 4;
    const bf16_t* aBase = &As[(wr * 64 + fr) * 32 + fq * 8];
    const bf16_t* bBase = &Bs[(wc * 64 + fr) * 32 + fq * 8];

    f32x4 acc[4][4] = {};

    for (int kk = 0; kk < K_len; kk += 32) {
        gload_lds16(gA0, lA0);
        gload_lds16(gA1, lA1);
        gA0 += 32;
        gA1 += 32;
        if (bvalid) {
            float4 v0 = *(const float4*)(gB);
            float4 v1 = *(const float4*)(gB + 4);
            float4 v2 = *(const float4*)(gB + 8);
            float4 v3 = *(const float4*)(gB + 12);
            gB += 32;
            bf16x8 p0, p1;
            p0[0] = (bf16_t)v0.x; p0[1] = (bf16_t)v0.y; p0[2] = (bf16_t)v0.z; p0[3] = (bf16_t)v0.w;
            p0[4] = (bf16_t)v1.x; p0[5] = (bf16_t)v1.y; p0[6] = (bf16_t)v1.z; p0[7] = (bf16_t)v1.w;
            p1[0] = (bf16_t)v2.x; p1[1] = (bf16_t)v2.y; p1[2] = (bf16_t)v2.z; p1[3] = (bf16_t)v2.w;
            p1[4] = (bf16_t)v3.x; p1[5] = (bf16_t)v3.y; p1[6] = (bf16_t)v3.z; p1[7] = (bf16_t)v3.w;
            *(bf16x8*)lB = p0;
            *((bf16x8*)lB + 1) = p1;
        }
        __syncthreads();
        bf16x8 af[4], bfr[4];
#pragma unroll
        for (int m = 0; m < 4; ++m) af[m] = *(const bf16x8*)(aBase + m * 512);
#pragma unroll
        for (int n = 0; n < 4; ++n) bfr[n] = *(const bf16x8*)(bBase + n * 512);
#pragma unroll
        for (int m = 0; m < 4; ++m)
#pragma unroll
            for (int n = 0; n < 4; ++n)
                acc[m][n] = __builtin_amdgcn_mfma_f32_16x16x32_bf16(af[m], bfr[n], acc[m][n], 0, 0, 0);
        __syncthreads();
    }

    float* Cz = C + ((gridDim.z > 1) ? (long)blockIdx.z * partial_stride : 0L);
#pragma unroll
    for (int m = 0; m < 4; ++m) {
        const int grow0 = m0 + wr * 64 + m * 16 + fq * 4;
#pragma unroll
        for (int n = 0; n < 4; ++n) {
            const int gcol = n0 + wc * 64 + n * 16 + fr;
            if (gcol >= N) continue;
            float bv = bias ? bias[gcol] : 0.f;
#pragma unroll
            for (int r = 0; r < 4; ++r) {
                long idx = (long)(grow0 + r) * ldc + gcol;
                float v = acc[m][n][r] + bv;
                if (out_bf16) {
                    ((bf16_t*)Cz)[idx] = (bf16_t)v;
                } else {
                    if (accumulate) v += Cz[idx];
                    Cz[idx] = v;
                }
            }
        }
    }
}

// ---------------------------------------------------------------- bf16xbf16 batched MFMA GEMM
__global__ __launch_bounds__(256, 2) void gemm_bb(
    const bf16_t* __restrict__ A, long aO, long aI, int lda,
    const bf16_t* __restrict__ B, long bO, long bI, int ldb,
    void* __restrict__ Cv, long cO, long cI, int ldc,
    int K_len, int out_bf16) {
    __shared__ bf16_t As[128 * 32];
    __shared__ bf16_t Bs[128 * 32];
    const int tid = threadIdx.x;
    const int lane = tid & 63;
    const int wave = tid >> 6;
    const int z = blockIdx.z, zb = z >> 2, zh = z & 3;
    const bf16_t* Az = A + (long)zb * aO + (long)zh * aI;
    const bf16_t* Bz = B + (long)zb * bO + (long)zh * bI;
    const int m0 = blockIdx.y * 128;
    const int n0 = blockIdx.x * 128;

    const int cA = wave * 2;
    const bf16_t* gA0 = Az + (long)(m0 + cA * 16 + (lane >> 2)) * lda + (lane & 3) * 8;
    const bf16_t* gA1 = gA0 + 16L * lda;
    const bf16_t* gB0 = Bz + (long)(n0 + cA * 16 + (lane >> 2)) * ldb + (lane & 3) * 8;
    const bf16_t* gB1 = gB0 + 16L * ldb;
    bf16_t* lA0 = &As[cA * 512];
    bf16_t* lA1 = lA0 + 512;
    bf16_t* lB0 = &Bs[cA * 512];
    bf16_t* lB1 = lB0 + 512;

    const int wr = wave >> 1, wc = wave & 1;
    const int fr = lane & 15, fq = lane >> 4;
    const bf16_t* aBase = &As[(wr * 64 + fr) * 32 + fq * 8];
    const bf16_t* bBase = &Bs[(wc * 64 + fr) * 32 + fq * 8];

    f32x4 acc[4][4] = {};

    for (int kk = 0; kk < K_len; kk += 32) {
        gload_lds16(gA0, lA0);
        gload_lds16(gA1, lA1);
        gload_lds16(gB0, lB0);
        gload_lds16(gB1, lB1);
        gA0 += 32; gA1 += 32; gB0 += 32; gB1 += 32;
        __syncthreads();
        bf16x8 af[4], bfr[4];
#pragma unroll
        for (int m = 0; m < 4; ++m) af[m] = *(const bf16x8*)(aBase + m * 512);
#pragma unroll
        for (int n = 0; n < 4; ++n) bfr[n] = *(const bf16x8*)(bBase + n * 512);
#pragma unroll
        for (int m = 0; m < 4; ++m)
#pragma unroll
            for (int n = 0; n < 4; ++n)
                acc[m][n] = __builtin_amdgcn_mfma_f32_16x16x32_bf16(af[m], bfr[n], acc[m][n], 0, 0, 0);
        __syncthreads();
    }

#pragma unroll
    for (int m = 0; m < 4; ++m) {
        const int grow0 = m0 + wr * 64 + m * 16 + fq * 4;
#pragma unroll
        for (int n = 0; n < 4; ++n) {
            const int gcol = n0 + wc * 64 + n * 16 + fr;
#pragma unroll
            for (int r = 0; r < 4; ++r) {
                long idx = (long)(grow0 + r) * ldc + gcol;
                if (out_bf16) {
                    bf16_t* Cb = (bf16_t*)Cv + (long)zb * cO + (long)zh * cI;
                    Cb[idx] = (bf16_t)acc[m][n][r];
                } else {
                    float* Cf = (float*)Cv + (long)zb * cO + (long)zh * cI;
                    Cf[idx] = acc[m][n][r];
                }
            }
        }
    }
}

// ---------------------------------------------------------------- V transpose (attention)
__global__ void vtrans_kernel(const bf16_t* __restrict__ qkvb, bf16_t* __restrict__ vt) {
    int z = blockIdx.z;  // b*4+h
    int b = z >> 2, h = z & 3;
    int d0 = blockIdx.x * 64, k0 = blockIdx.y * 64;
    __shared__ bf16_t tile[64][72];
    int t = threadIdx.x;  // 256
    int r = t >> 2;
    int c4 = (t & 3) * 16;
    const bf16_t* src = qkvb + ((long)(b * SEQL + k0 + r)) * (3 * D_MODEL) + 2 * D_MODEL +
                        h * HEAD_DIM + d0 + c4;
    bf16x8 v0 = *(const bf16x8*)src;
    bf16x8 v1 = *(const bf16x8*)(src + 8);
#pragma unroll
    for (int j = 0; j < 8; ++j) tile[r][c4 + j] = v0[j];
#pragma unroll
    for (int j = 0; j < 8; ++j) tile[r][c4 + 8 + j] = v1[j];
    __syncthreads();
    int dd = t >> 2, kc = (t & 3) * 16;
    bf16_t* dst = vt + (long)z * (HEAD_DIM * SEQL) + (long)(d0 + dd) * SEQL + k0 + kc;
    bf16x8 o0, o1;
#pragma unroll
    for (int j = 0; j < 8; ++j) o0[j] = tile[kc + j][dd];
#pragma unroll
    for (int j = 0; j < 8; ++j) o1[j] = tile[kc + 8 + j][dd];
    *(bf16x8*)dst = o0;
    *(bf16x8*)(dst + 8) = o1;
}

// ---------------------------------------------------------------- softmax rows of S
__global__ void softmax_kernel(const float* __restrict__ S, bf16_t* __restrict__ P) {
    long row = blockIdx.x;  // 4096 = (b,h,q)
    int tid = threadIdx.x;  // 256
    float s = S[row * SEQL + tid] * 0.044194173824159216f;  // 1/sqrt(512)
    __shared__ float red[4];
    float m = warp_reduce_max(s);
    if ((tid & 63) == 0) red[tid >> 6] = m;
    __syncthreads();
    float gm = fmaxf(fmaxf(red[0], red[1]), fmaxf(red[2], red[3]));
    __syncthreads();
    float p = __expf(s - gm);
    float su = warp_reduce_sum(p);
    if ((tid & 63) == 0) red[tid >> 6] = su;
    __syncthreads();
    float gs = red[0] + red[1] + red[2] + red[3];
    P[row * SEQL + tid] = (bf16_t)(p / gs);
}

// ---------------------------------------------------------------- conv + silu + transpose
__global__ void conv_tr_kernel(const bf16_t* __restrict__ xzb, const float* __restrict__ cw,
                               const float* __restrict__ cb, bf16_t* __restrict__ xT,
                               bf16_t* __restrict__ xcb, bf16_t* __restrict__ zT) {
    __shared__ bf16_t xin[68][64];
    __shared__ bf16_t outt[64][72];  // [e_local][l_local]
    const int e0 = blockIdx.x * 64, l0 = blockIdx.y * 64, b = blockIdx.z;
    const int t = threadIdx.x;
    const int r = t >> 4;            // 0..15
    const int c = (t & 15) * 4;      // 0..60

#pragma unroll
    for (int i = 0; i < 5; ++i) {
        int m = r + i * 16;
        if (m < 67) {
            int l = l0 - 3 + m;
            bf16x4 v;
            if (l >= 0)
                v = *(const bf16x4*)(xzb + ((long)(b * SEQL + l)) * (2 * ED) + e0 + c);
            else {
                v[0] = (bf16_t)0.f; v[1] = (bf16_t)0.f; v[2] = (bf16_t)0.f; v[3] = (bf16_t)0.f;
            }
            *(bf16x4*)&xin[m][c] = v;
        }
    }
    __syncthreads();

    {
        const int e_l = t & 63;
        const int lbase = (t >> 6) * 16;
        const float4 wv = *(const float4*)(cw + (long)(e0 + e_l) * 4);
        const float bias = cb[e0 + e_l];
#pragma unroll
        for (int k = 0; k < 16; ++k) {
            int l = lbase + k;
            float acc = bias + wv.x * (float)xin[l][e_l] + wv.y * (float)xin[l + 1][e_l] +
                        wv.z * (float)xin[l + 2][e_l] + wv.w * (float)xin[l + 3][e_l];
            float s = acc / (1.f + __expf(-acc));
            outt[e_l][l] = (bf16_t)s;
        }
    }
    __syncthreads();

    {
        int er = t >> 2, lc = (t & 3) * 16;
        bf16x8 a = *(bf16x8*)&outt[er][lc];
        bf16x8 bb8 = *(bf16x8*)&outt[er][lc + 8];
        bf16_t* dst = xT + ((long)b * ED + e0 + er) * SEQL + l0 + lc;
        *(bf16x8*)dst = a;
        *(bf16x8*)(dst + 8) = bb8;
    }
    {
        int lr = t >> 2, ec = (t & 3) * 16;
        bf16_t tmp[16];
#pragma unroll
        for (int j = 0; j < 16; ++j) tmp[j] = outt[ec + j][lr];
        bf16_t* dst = xcb + ((long)(b * SEQL + l0 + lr)) * ED + e0 + ec;
        *(bf16x8*)dst = *(bf16x8*)&tmp[0];
        *(bf16x8*)(dst + 8) = *(bf16x8*)&tmp[8];
    }
    __syncthreads();

#pragma unroll
    for (int i = 0; i < 4; ++i) {
        int m = r + i * 16;
        bf16x4 v = *(const bf16x4*)(xzb + ((long)(b * SEQL + l0 + m)) * (2 * ED) + ED + e0 + c);
        *(bf16x4*)&xin[m][c] = v;
    }
    __syncthreads();
    {
        int er = t >> 2, lc = (t & 3) * 16;
        bf16_t tz[16];
#pragma unroll
        for (int j = 0; j < 16; ++j) tz[j] = xin[lc + j][er];
        bf16_t* dst = zT + ((long)b * ED + e0 + er) * SEQL + l0 + lc;
        *(bf16x8*)dst = *(bf16x8*)&tz[0];
        *(bf16x8*)(dst + 8) = *(bf16x8*)&tz[8];
    }
}

// ---------------------------------------------------------------- softplus + transpose
__global__ void softplus_tr_kernel(const float* __restrict__ delta, const float* __restrict__ dt_b,
                                   float* __restrict__ dT) {
    __shared__ float tile[64][65];
    const int e0 = blockIdx.x * 64, l0 = blockIdx.y * 64, b = blockIdx.z;
    const int t = threadIdx.x;
    const int r = t >> 4, c = (t & 15) * 4;
#pragma unroll
    for (int i = 0; i < 4; ++i) {
        int l = r + i * 16;
        float4 v = *(const float4*)(delta + ((long)(b * SEQL + l0 + l)) * ED + e0 + c);
        float4 bb = *(const float4*)(dt_b + e0 + c);
        float u0 = v.x + bb.x, u1 = v.y + bb.y, u2 = v.z + bb.z, u3 = v.w + bb.w;
        tile[l][c] = (u0 > 20.f) ? u0 : log1pf(__expf(u0));
        tile[l][c + 1] = (u1 > 20.f) ? u1 : log1pf(__expf(u1));
        tile[l][c + 2] = (u2 > 20.f) ? u2 : log1pf(__expf(u2));
        tile[l][c + 3] = (u3 > 20.f) ? u3 : log1pf(__expf(u3));
    }
    __syncthreads();
#pragma unroll
    for (int i = 0; i < 4; ++i) {
        int ee = r + i * 16;
        float4 w;
        w.x = tile[c][ee];
        w.y = tile[c + 1][ee];
        w.z = tile[c + 2][ee];
        w.w = tile[c + 3][ee];
        *(float4*)(dT + ((long)b * ED + e0 + ee) * SEQL + l0 + c) = w;
    }
}

// ---------------------------------------------------------------- chunk-parallel selective scan
// lane owns (e, chunk): 16 chunks of 16 steps; B/C staged in LDS with PERMUTED rows:
// LDS row lrow(l) = (l&15)*16 + (l>>4), so chunk-lanes (same j, diff chunk) read ADJACENT
// rows (stride 36 floats -> 4*chunk bank spread -> 2-way max, vs 16-way with linear rows).
// grid = (ED/16, B); block = 256.
__global__ __launch_bounds__(256) void scan_chunk_kernel(
    const float* __restrict__ dT, const bf16_t* __restrict__ xT, const bf16_t* __restrict__ zT,
    const float* __restrict__ dbc, const float* __restrict__ A_log, const float* __restrict__ Dp,
    bf16_t* __restrict__ yT) {
    __shared__ float bc[SEQL][36];  // permuted rows; cols 0..15 = B, 16..31 = C
    const int t = threadIdx.x;
    const int chunk = t & 15;
    const int el = t >> 4;
    const int b = blockIdx.y;
    const int e = blockIdx.x * 16 + el;
    const int l0 = chunk * 16;
    const int R = DT_RANK + 2 * D_STATE;  // 160

    // ---- stage dbc B/C columns into LDS at permuted rows
    {
        const int row0 = t >> 3;
        const int col = (t & 7) * 4;
        const float* src = dbc + (long)b * SEQL * R + DT_RANK;
#pragma unroll
        for (int it = 0; it < 8; ++it) {
            int row = row0 + it * 32;
            int prow = ((row & 15) << 4) | (row >> 4);
            *(float4*)&bc[prow][col] = *(const float4*)(src + (long)row * R + col);
        }
    }

    float Ar[16];
    {
        const float* ap = A_log + (long)e * D_STATE;
#pragma unroll
        for (int n = 0; n < 16; n += 4) {
            float4 v = *(const float4*)(ap + n);
            Ar[n] = -__expf(v.x);
            Ar[n + 1] = -__expf(v.y);
            Ar[n + 2] = -__expf(v.z);
            Ar[n + 3] = -__expf(v.w);
        }
    }
    float d[16];
    {
        const float* dp = dT + ((long)b * ED + e) * SEQL + l0;
#pragma unroll
        for (int j = 0; j < 16; j += 4) *(float4*)&d[j] = *(const float4*)(dp + j);
    }
    float xf[16];
    {
        const bf16_t* xp = xT + ((long)b * ED + e) * SEQL + l0;
        bf16x8 x0 = *(const bf16x8*)xp;
        bf16x8 x1 = *(const bf16x8*)(xp + 8);
#pragma unroll
        for (int j = 0; j < 8; ++j) {
            xf[j] = (float)x0[j];
            xf[8 + j] = (float)x1[j];
        }
    }
    __syncthreads();

    float P[16], S[16];
#pragma unroll
    for (int n = 0; n < 16; ++n) {
        P[n] = 1.f;
        S[n] = 0.f;
    }

    // pass A: per-chunk summary from h=0 (B from LDS; row j*16+chunk)
#pragma unroll
    for (int j = 0; j < 16; ++j) {
        const float* br = &bc[(j << 4) | chunk][0];
        float dj = d[j];
        float dx = dj * xf[j];
#pragma unroll
        for (int n = 0; n < 16; ++n) {
            float dA = __expf(dj * Ar[n]);
            S[n] = dA * S[n] + dx * br[n];
            P[n] *= dA;
        }
    }

    // combine: inclusive scan over 16 chunk-lanes
#pragma unroll
    for (int off = 1; off < 16; off <<= 1) {
        float Pp[16], Sp[16];
#pragma unroll
        for (int n = 0; n < 16; ++n) {
            Pp[n] = __shfl_up(P[n], off, 16);
            Sp[n] = __shfl_up(S[n], off, 16);
        }
        if (chunk >= off) {
#pragma unroll
            for (int n = 0; n < 16; ++n) {
                S[n] = P[n] * Sp[n] + S[n];
                P[n] *= Pp[n];
            }
        }
    }

    // exclusive: h_init[chunk] = inclusive_S[chunk-1]
    float h[16];
#pragma unroll
    for (int n = 0; n < 16; ++n) {
        float hs = __shfl_up(S[n], 1, 16);
        h[n] = (chunk == 0) ? 0.f : hs;
    }

    const float dpe = Dp[e];
    float yf[16];
    // pass C: replay with true h_init (B,C from LDS; row j*16+chunk)
#pragma unroll
    for (int j = 0; j < 16; ++j) {
        const float* br = &bc[(j << 4) | chunk][0];
        float dj = d[j];
        float dx = dj * xf[j];
        float y = 0.f;
#pragma unroll
        for (int n = 0; n < 16; ++n) {
            float dA = __expf(dj * Ar[n]);
            h[n] = dA * h[n] + dx * br[n];
            y += h[n] * br[16 + n];
        }
        yf[j] = y + xf[j] * dpe;
    }

    // epilogue: gate with silu(z), 8 at a time (keeps z out of the hot live range)
    const bf16_t* zp = zT + ((long)b * ED + e) * SEQL + l0;
    bf16_t* yp = yT + ((long)b * ED + e) * SEQL + l0;
    {
        bf16x8 z0 = *(const bf16x8*)zp;
        bf16x8 o0;
#pragma unroll
        for (int j = 0; j < 8; ++j) {
            float z = (float)z0[j];
            o0[j] = (bf16_t)(yf[j] * (z / (1.f + __expf(-z))));
        }
        *(bf16x8*)yp = o0;
        bf16x8 z1 = *(const bf16x8*)(zp + 8);
        bf16x8 o1;
#pragma unroll
        for (int j = 0; j < 8; ++j) {
            float z = (float)z1[j];
            o1[j] = (bf16_t)(yf[8 + j] * (z / (1.f + __expf(-z))));
        }
        *(bf16x8*)(yp + 8) = o1;
    }
}

// ---------------------------------------------------------------- yT [B][ED][L] -> Y [B*L][ED]
__global__ void ytr_kernel(const bf16_t* __restrict__ yT, bf16_t* __restrict__ Y) {
    __shared__ bf16_t tl[64][72];
    const int e0 = blockIdx.x * 64, l0 = blockIdx.y * 64, b = blockIdx.z;
    const int t = threadIdx.x;
    {
        int er = t >> 2, lc = (t & 3) * 16;
        const bf16_t* src = yT + ((long)b * ED + e0 + er) * SEQL + l0 + lc;
        bf16x8 a = *(const bf16x8*)src;
        bf16x8 bb8 = *(const bf16x8*)(src + 8);
        *(bf16x8*)&tl[er][lc] = a;
        *(bf16x8*)&tl[er][lc + 8] = bb8;
    }
    __syncthreads();
    {
        int lr = t >> 2, ec = (t & 3) * 16;
        bf16_t tmp[16];
#pragma unroll
        for (int j = 0; j < 16; ++j) tmp[j] = tl[ec + j][lr];
        bf16_t* dst = Y + ((long)(b * SEQL + l0 + lr)) * ED + e0 + ec;
        *(bf16x8*)dst = *(bf16x8*)&tmp[0];
        *(bf16x8*)(dst + 8) = *(bf16x8*)&tmp[8];
    }
}

// ---------------------------------------------------------------- head GEMV1
__global__ void head_gemv1(const float* __restrict__ H, const float* __restrict__ w1,
                           const float* __restrict__ b1, float* __restrict__ hm1) {
    int b = blockIdx.y;
    int wave = threadIdx.x >> 6, lane = threadIdx.x & 63;
    int n = blockIdx.x * 4 + wave;
    const float* last = H + ((long)(b * SEQL + SEQL - 1)) * D_MODEL;
    const float* wr = w1 + (long)n * D_MODEL;
    float s = 0.f;
    for (int j = lane * 4; j < D_MODEL; j += 256) {
        float4 a = *(const float4*)(last + j);
        float4 w = *(const float4*)(wr + j);
        s += a.x * w.x + a.y * w.y + a.z * w.z + a.w * w.w;
    }
    s = warp_reduce_sum(s);
    if (lane == 0) hm1[b * 1024 + n] = s + b1[n];
}

// ---------------------------------------------------------------- head final
__global__ void head_final(const float* __restrict__ hm1, const float* __restrict__ ln_g,
                           const float* __restrict__ ln_b, const float* __restrict__ w2,
                           const float* __restrict__ b2, float* __restrict__ out) {
    int b = blockIdx.x;
    int tid = threadIdx.x;  // 1024
    __shared__ float hm[1024];
    __shared__ float r1[16], r2[16];
    __shared__ float stats[2];
    __shared__ float outs[64];

    float v = hm1[b * 1024 + tid];
    float s1 = warp_reduce_sum(v);
    float s2 = warp_reduce_sum(v * v);
    int wave = tid >> 6;
    if ((tid & 63) == 0) { r1[wave] = s1; r2[wave] = s2; }
    __syncthreads();
    if (tid == 0) {
        float t1 = 0.f, t2 = 0.f;
        for (int w = 0; w < 16; ++w) { t1 += r1[w]; t2 += r2[w]; }
        float mean = t1 / 1024.f;
        stats[0] = mean;
        stats[1] = rsqrtf(t2 / 1024.f - mean * mean + 1e-5f);
    }
    __syncthreads();
    float x = (v - stats[0]) * stats[1] * ln_g[tid] + ln_b[tid];
    x = (x > 0.f) ? x : (__expf(x) - 1.f);
    hm[tid] = x;
    __syncthreads();

    int o = tid >> 4, kk = tid & 15;
    float a = 0.f;
    const float* w2r = w2 + (long)o * 1024;
    for (int j = kk; j < 1024; j += 16) a += hm[j] * w2r[j];
#pragma unroll
    for (int off = 1; off < 16; off <<= 1) a += __shfl_xor(a, off);
    if (kk == 0) outs[o] = a + b2[o];
    __syncthreads();
    if (tid < 64) {
        float vv = outs[tid];
        float ss = warp_reduce_sum(vv * vv);
        out[b * 64 + tid] = vv / fmaxf(sqrtf(ss), 1e-12f);
    }
}

// ---------------------------------------------------------------- launch
extern "C" void kernel_launch(void* const* d_in, const int* in_sizes, int n_in,
                              void* d_out, int out_size, void* d_ws, size_t ws_size,
                              hipStream_t stream) {
    const float* x = (const float*)d_in[0];
    const float* norm_w = (const float*)d_in[1];
    const float* in_proj_w = (const float*)d_in[2];
    const float* conv_w = (const float*)d_in[3];
    const float* conv_b = (const float*)d_in[4];
    const float* x_proj_w = (const float*)d_in[5];
    const float* dt_proj_w = (const float*)d_in[6];
    const float* dt_proj_b = (const float*)d_in[7];
    const float* A_log = (const float*)d_in[8];
    const float* D_param = (const float*)d_in[9];
    const float* out_proj_w = (const float*)d_in[10];
    const float* attn_in_w = (const float*)d_in[11];
    const float* attn_in_b = (const float*)d_in[12];
    const float* attn_out_w = (const float*)d_in[13];
    const float* attn_out_b = (const float*)d_in[14];
    const float* w1 = (const float*)d_in[15];
    const float* b1 = (const float*)d_in[16];
    const float* ln_g = (const float*)d_in[17];
    const float* ln_b = (const float*)d_in[18];
    const float* w2 = (const float*)d_in[19];
    const float* b2 = (const float*)d_in[20];

    float* ws = (float*)d_ws;
    size_t o = 0;
    float* H = ws + o;      o += 2097152;       // (B,L,D) fp32
    float* SCR = ws + o;    o += 6291456;       // XZb/dT/yT (mamba) | QKV etc (attn) | splitK partials
    float* DELTA = ws + o;  o += 4194304;       // (B,L,ED) fp32  (contiguous after SCR)
    float* DBC = ws + o;    o += 163840;        // (B,L,160) fp32
    float* XPART = ws + o;  o += 1310720;       // 8 x (1024,160) split-K partials
    bf16_t* XNb = (bf16_t*)(ws + o);  o += 1048576;  // (B,L,D) bf16
    bf16_t* XCb = (bf16_t*)(ws + o);  o += 2097152;  // (B,L,ED) bf16
    bf16_t* DTb = (bf16_t*)(ws + o);  o += 65536;    // (1024,128) bf16
    bf16_t* Yb = (bf16_t*)(ws + o);   o += 2097152;  // (B,L,ED) bf16
    bf16_t* Hb = (bf16_t*)(ws + o);   o += 1048576;  // (B,L,D) bf16
    bf16_t* AOb = (bf16_t*)(ws + o);  o += 1048576;  // (B,L,D) bf16
    float* HM1 = ws + o;    o += 4096;          // (B,1024) fp32
    bf16_t* XT = (bf16_t*)(ws + o);   o += 2097152;  // [B][ED][L] bf16
    bf16_t* ZT = (bf16_t*)(ws + o);   o += 2097152;  // [B][ED][L] bf16

    bf16_t* XZb = (bf16_t*)SCR;                       // [B*L][2ED] bf16 (dead after conv_tr)
    float* DTT = SCR;                                 // [B][ED][L] f32 (aliases XZb; written after)
    bf16_t* YTT = (bf16_t*)(SCR + 4194304);           // [B][ED][L] bf16
    float* PART = SCR;                                // splitK partials (SCR+DELTA contiguous)

    bf16_t* QKVb = (bf16_t*)SCR;                      // attention phase
    float* SBUF = SCR + 3145728;
    bf16_t* Pb = (bf16_t*)(SCR + 3145728 + 1048576);
    bf16_t* VTb = (bf16_t*)(SCR + 3145728 + 1048576 + 524288);

    const int M = BATCH * SEQL;  // 1024
    const long S_H = (long)M * D_MODEL;

    copy_kernel<<<(S_H + 255) / 256, 256, 0, stream>>>(x, H, (int)S_H);

    for (int i = 0; i < N_LAYERS; ++i) {
        rmsnorm_kernel<<<M, 256, 0, stream>>>(H, norm_w + (long)i * D_MODEL, XNb);
        gemm_bf16<<<dim3(64, 8, 1), 256, 0, stream>>>(
            XNb, D_MODEL, in_proj_w + (long)i * 2 * ED * D_MODEL, D_MODEL, (float*)XZb, 2 * ED,
            2 * ED, D_MODEL, nullptr, 0, 1, 0);
        conv_tr_kernel<<<dim3(64, 4, 4), 256, 0, stream>>>(
            XZb, conv_w + (long)i * ED * D_CONV, conv_b + (long)i * ED, XT, XCb, ZT);
        gemm_bf16<<<dim3(2, 8, 8), 256, 0, stream>>>(
            XCb, ED, x_proj_w + (long)i * (DT_RANK + 2 * D_STATE) * ED, ED, XPART,
            DT_RANK + 2 * D_STATE, DT_RANK + 2 * D_STATE, ED / 8, nullptr, 0, 0,
            (long)M * (DT_RANK + 2 * D_STATE));
        ksum_kernel<<<640, 256, 0, stream>>>(XPART, DBC, M * (DT_RANK + 2 * D_STATE), 8,
                                             (long)M * (DT_RANK + 2 * D_STATE));
        dt_pack_kernel<<<512, 256, 0, stream>>>(DBC, DTb);
        gemm_bf16<<<dim3(32, 8, 1), 256, 0, stream>>>(
            DTb, DT_RANK, dt_proj_w + (long)i * ED * DT_RANK, DT_RANK, DELTA, ED, ED, DT_RANK,
            nullptr, 0, 0, 0);
        softplus_tr_kernel<<<dim3(64, 4, 4), 256, 0, stream>>>(DELTA, dt_proj_b + (long)i * ED,
                                                               DTT);
        scan_chunk_kernel<<<dim3(ED / 16, BATCH), 256, 0, stream>>>(
            DTT, XT, ZT, DBC, A_log + (long)i * ED * D_STATE, D_param + (long)i * ED, YTT);
        ytr_kernel<<<dim3(64, 4, 4), 256, 0, stream>>>(YTT, Yb);
        // out_proj: split-K=4 (512 blocks) -> fp32 partials over dead SCR/DELTA, then add into H
        gemm_bf16<<<dim3(16, 8, 4), 256, 0, stream>>>(
            Yb, ED, out_proj_w + (long)i * D_MODEL * ED, ED, PART, D_MODEL, D_MODEL, ED / 4,
            nullptr, 0, 0, (long)M * D_MODEL);
        ksum_add_kernel<<<8192, 256, 0, stream>>>(PART, H, M * D_MODEL, 4, (long)M * D_MODEL,
                                                  nullptr, 0);
    }

    f2b_kernel<<<(int)((S_H + 255) / 256), 256, 0, stream>>>(H, Hb, (int)S_H);
    gemm_bf16<<<dim3(48, 8, 1), 256, 0, stream>>>(Hb, D_MODEL, attn_in_w, D_MODEL, (float*)QKVb,
                                                  3 * D_MODEL, 3 * D_MODEL, D_MODEL, attn_in_b, 0,
                                                  1, 0);
    vtrans_kernel<<<dim3(8, 4, 16), 256, 0, stream>>>(QKVb, VTb);
    gemm_bb<<<dim3(2, 2, 16), 256, 0, stream>>>(
        QKVb, (long)SEQL * 3 * D_MODEL, HEAD_DIM, 3 * D_MODEL,
        QKVb + D_MODEL, (long)SEQL * 3 * D_MODEL, HEAD_DIM, 3 * D_MODEL,
        SBUF, 4L * SEQL * SEQL, (long)SEQL * SEQL, SEQL, HEAD_DIM, 0);
    softmax_kernel<<<BATCH * N_HEADS * SEQL, 256, 0, stream>>>(SBUF, Pb);
    gemm_bb<<<dim3(4, 2, 16), 256, 0, stream>>>(
        Pb, 4L * SEQL * SEQL, (long)SEQL * SEQL, SEQL,
        VTb, 4L * HEAD_DIM * SEQL, (long)HEAD_DIM * SEQL, SEQL,
        AOb, (long)SEQL * D_MODEL, HEAD_DIM, D_MODEL, SEQL, 1);
    // attn_out: split-K=4 (512 blocks); bias folded into the reduce (added once)
    gemm_bf16<<<dim3(16, 8, 4), 256, 0, stream>>>(
        AOb, D_MODEL, attn_out_w, D_MODEL, PART, D_MODEL, D_MODEL, D_MODEL / 4, nullptr, 0, 0,
        (long)M * D_MODEL);
    ksum_add_kernel<<<8192, 256, 0, stream>>>(PART, H, M * D_MODEL, 4, (long)M * D_MODEL,
                                              attn_out_b, D_MODEL - 1);

    head_gemv1<<<dim3(256, 4), 256, 0, stream>>>(H, w1, b1, HM1);
    head_final<<<BATCH, 1024, 0, stream>>>(HM1, ln_g, ln_b, w2, b2, (float*)d_out);
}

// Round 9
// 677.334 us; speedup vs baseline: 1.3074x; 1.1361x over previous
//
#include <hip/hip_runtime.h>
#include <hip/hip_bf16.h>
#include <math.h>

#define D_MODEL 2048
#define N_LAYERS 2
#define ED 4096
#define D_STATE 16
#define D_CONV 4
#define DT_RANK 128
#define N_HEADS 4
#define HEAD_DIM 512
#define BATCH 4
#define SEQL 256

typedef __bf16 bf16_t;
typedef bf16_t bf16x8 __attribute__((ext_vector_type(8)));
typedef bf16_t bf16x4 __attribute__((ext_vector_type(4)));
typedef float f32x4 __attribute__((ext_vector_type(4)));

// ---------------------------------------------------------------- utilities
__device__ __forceinline__ float warp_reduce_sum(float v) {
#pragma unroll
    for (int off = 1; off < 64; off <<= 1) v += __shfl_xor(v, off);
    return v;
}
__device__ __forceinline__ float warp_reduce_max(float v) {
#pragma unroll
    for (int off = 1; off < 64; off <<= 1) v = fmaxf(v, __shfl_xor(v, off));
    return v;
}

__device__ __forceinline__ void gload_lds16(const bf16_t* g, bf16_t* l) {
    __builtin_amdgcn_global_load_lds(
        (const __attribute__((address_space(1))) unsigned int*)g,
        (__attribute__((address_space(3))) unsigned int*)l, 16, 0, 0);
}

// ---------------------------------------------------------------- copy / convert
__global__ void copy_kernel(const float* __restrict__ src, float* __restrict__ dst, int n) {
    int i = blockIdx.x * blockDim.x + threadIdx.x;
    if (i < n) dst[i] = src[i];
}

__global__ void f2b_kernel(const float* __restrict__ src, bf16_t* __restrict__ dst, int n) {
    int i = blockIdx.x * blockDim.x + threadIdx.x;
    if (i < n) dst[i] = (bf16_t)src[i];
}

// vectorized fp32 -> bf16 (8 per thread); n must be multiple of 8*gridsize
__global__ void f2b8_kernel(const float* __restrict__ src, bf16_t* __restrict__ dst, long n8) {
    long i = (long)blockIdx.x * blockDim.x + threadIdx.x;
    if (i >= n8) return;
    float4 a = ((const float4*)src)[2 * i];
    float4 b = ((const float4*)src)[2 * i + 1];
    bf16x8 o;
    o[0] = (bf16_t)a.x; o[1] = (bf16_t)a.y; o[2] = (bf16_t)a.z; o[3] = (bf16_t)a.w;
    o[4] = (bf16_t)b.x; o[5] = (bf16_t)b.y; o[6] = (bf16_t)b.z; o[7] = (bf16_t)b.w;
    ((bf16x8*)dst)[i] = o;
}

__global__ void dt_pack_kernel(const float* __restrict__ dbc, bf16_t* __restrict__ dt) {
    int i = blockIdx.x * blockDim.x + threadIdx.x;  // < 1024*128
    int row = i >> 7, col = i & 127;
    dt[i] = (bf16_t)dbc[row * (DT_RANK + 2 * D_STATE) + col];
}

__global__ void ksum_kernel(const float* __restrict__ part, float* __restrict__ out, int n,
                            int nz, long stride) {
    int i = blockIdx.x * blockDim.x + threadIdx.x;
    if (i >= n) return;
    float s = 0.f;
    for (int z = 0; z < nz; ++z) s += part[(long)z * stride + i];
    out[i] = s;
}

__global__ void ksum_add_kernel(const float* __restrict__ part, float* __restrict__ out, int n,
                                int nz, long stride, const float* __restrict__ bias, int bmask) {
    int i = blockIdx.x * blockDim.x + threadIdx.x;
    if (i >= n) return;
    float s = out[i];
    for (int z = 0; z < nz; ++z) s += part[(long)z * stride + i];
    if (bias) s += bias[i & bmask];
    out[i] = s;
}

// ---------------------------------------------------------------- rmsnorm (bf16 out)
__global__ void rmsnorm_kernel(const float* __restrict__ x, const float* __restrict__ w,
                               bf16_t* __restrict__ o) {
    int row = blockIdx.x;
    int tid = threadIdx.x;  // 256
    const float* xr = x + (long)row * D_MODEL;
    float ss = 0.f;
    for (int i = tid; i < D_MODEL; i += 256) { float v = xr[i]; ss += v * v; }
    ss = warp_reduce_sum(ss);
    __shared__ float r[4];
    int wave = tid >> 6;
    if ((tid & 63) == 0) r[wave] = ss;
    __syncthreads();
    float tot = r[0] + r[1] + r[2] + r[3];
    float sc = rsqrtf(tot / (float)D_MODEL + 1e-5f);
    bf16_t* orow = o + (long)row * D_MODEL;
    for (int i = tid; i < D_MODEL; i += 256) orow[i] = (bf16_t)(xr[i] * sc * w[i]);
}

// ---------------------------------------------------------------- bf16 MFMA GEMM (fp32 B weights)
// kept for x_proj / dt_proj (small N / small K)
__global__ __launch_bounds__(256, 2) void gemm_bf16(
    const bf16_t* __restrict__ A, int lda, const float* __restrict__ B, int ldb,
    float* __restrict__ C, int ldc, int N, int K_len, const float* __restrict__ bias,
    int accumulate, int out_bf16, long partial_stride) {
    __shared__ bf16_t As[128 * 32];
    __shared__ bf16_t Bs[128 * 32];
    const int tid = threadIdx.x;
    const int lane = tid & 63;
    const int wave = tid >> 6;
    const int m0 = blockIdx.y * 128;
    const int n0 = blockIdx.x * 128;
    const int kbeg = blockIdx.z * K_len;

    const int cA = wave * 2;
    const bf16_t* gA0 = A + (long)(m0 + cA * 16 + (lane >> 2)) * lda + kbeg + (lane & 3) * 8;
    const bf16_t* gA1 = gA0 + 16L * lda;
    bf16_t* lA0 = &As[cA * 512];
    bf16_t* lA1 = &As[cA * 512 + 512];

    const int brow = tid >> 1;
    const int bcol = (tid & 1) * 16;
    const bool bvalid = (n0 + brow) < N;
    const float* gB = B + (long)(n0 + brow) * ldb + kbeg + bcol;
    bf16_t* lB = &Bs[brow * 32 + bcol];

    const int wr = wave >> 1, wc = wave & 1;
    const int fr = lane & 15, fq = lane >> 4;
    const bf16_t* aBase = &As[(wr * 64 + fr) * 32 + fq * 8];
    const bf16_t* bBase = &Bs[(wc * 64 + fr) * 32 + fq * 8];

    f32x4 acc[4][4] = {};

    for (int kk = 0; kk < K_len; kk += 32) {
        gload_lds16(gA0, lA0);
        gload_lds16(gA1, lA1);
        gA0 += 32;
        gA1 += 32;
        if (bvalid) {
            float4 v0 = *(const float4*)(gB);
            float4 v1 = *(const float4*)(gB + 4);
            float4 v2 = *(const float4*)(gB + 8);
            float4 v3 = *(const float4*)(gB + 12);
            gB += 32;
            bf16x8 p0, p1;
            p0[0] = (bf16_t)v0.x; p0[1] = (bf16_t)v0.y; p0[2] = (bf16_t)v0.z; p0[3] = (bf16_t)v0.w;
            p0[4] = (bf16_t)v1.x; p0[5] = (bf16_t)v1.y; p0[6] = (bf16_t)v1.z; p0[7] = (bf16_t)v1.w;
            p1[0] = (bf16_t)v2.x; p1[1] = (bf16_t)v2.y; p1[2] = (bf16_t)v2.z; p1[3] = (bf16_t)v2.w;
            p1[4] = (bf16_t)v3.x; p1[5] = (bf16_t)v3.y; p1[6] = (bf16_t)v3.z; p1[7] = (bf16_t)v3.w;
            *(bf16x8*)lB = p0;
            *((bf16x8*)lB + 1) = p1;
        }
        __syncthreads();
        bf16x8 af[4], bfr[4];
#pragma unroll
        for (int m = 0; m < 4; ++m) af[m] = *(const bf16x8*)(aBase + m * 512);
#pragma unroll
        for (int n = 0; n < 4; ++n) bfr[n] = *(const bf16x8*)(bBase + n * 512);
#pragma unroll
        for (int m = 0; m < 4; ++m)
#pragma unroll
            for (int n = 0; n < 4; ++n)
                acc[m][n] = __builtin_amdgcn_mfma_f32_16x16x32_bf16(af[m], bfr[n], acc[m][n], 0, 0, 0);
        __syncthreads();
    }

    float* Cz = C + ((gridDim.z > 1) ? (long)blockIdx.z * partial_stride : 0L);
#pragma unroll
    for (int m = 0; m < 4; ++m) {
        const int grow0 = m0 + wr * 64 + m * 16 + fq * 4;
#pragma unroll
        for (int n = 0; n < 4; ++n) {
            const int gcol = n0 + wc * 64 + n * 16 + fr;
            if (gcol >= N) continue;
            float bv = bias ? bias[gcol] : 0.f;
#pragma unroll
            for (int r = 0; r < 4; ++r) {
                long idx = (long)(grow0 + r) * ldc + gcol;
                float v = acc[m][n][r] + bv;
                if (out_bf16) {
                    ((bf16_t*)Cz)[idx] = (bf16_t)v;
                } else {
                    if (accumulate) v += Cz[idx];
                    Cz[idx] = v;
                }
            }
        }
    }
}

// ---------------------------------------------------------------- bf16 x bf16 weight GEMM, BM=64
// C[M,N] = A[M,K](bf16,lda) * B[N,K](bf16,ldb)^T. Tile 64x128, 4 waves of 32x64.
// gridDim.z>1 => fp32 split-K partials at Cv + z*partial_stride (bias ignored then).
__global__ __launch_bounds__(256, 4) void gemm_w64(
    const bf16_t* __restrict__ A, int lda, const bf16_t* __restrict__ B, int ldb,
    void* __restrict__ Cv, int ldc, int K_len, const float* __restrict__ bias,
    int out_bf16, long partial_stride) {
    __shared__ bf16_t As[64 * 32];
    __shared__ bf16_t Bs[128 * 32];
    const int tid = threadIdx.x;
    const int lane = tid & 63;
    const int wave = tid >> 6;
    const int m0 = blockIdx.y * 64;
    const int n0 = blockIdx.x * 128;
    const int kbeg = blockIdx.z * K_len;

    const bf16_t* gA = A + (long)(m0 + wave * 16 + (lane >> 2)) * lda + kbeg + (lane & 3) * 8;
    bf16_t* lA = &As[wave * 512];
    const bf16_t* gB0 = B + (long)(n0 + wave * 32 + (lane >> 2)) * ldb + kbeg + (lane & 3) * 8;
    const bf16_t* gB1 = gB0 + 16L * ldb;
    bf16_t* lB0 = &Bs[wave * 1024];
    bf16_t* lB1 = lB0 + 512;

    const int wr = wave >> 1, wc = wave & 1;
    const int fr = lane & 15, fq = lane >> 4;
    const bf16_t* aBase = &As[(wr * 32 + fr) * 32 + fq * 8];
    const bf16_t* bBase = &Bs[(wc * 64 + fr) * 32 + fq * 8];

    f32x4 acc[2][4] = {};

    for (int kk = 0; kk < K_len; kk += 32) {
        gload_lds16(gA, lA);
        gload_lds16(gB0, lB0);
        gload_lds16(gB1, lB1);
        gA += 32; gB0 += 32; gB1 += 32;
        __syncthreads();
        bf16x8 af[2], bfr[4];
#pragma unroll
        for (int m = 0; m < 2; ++m) af[m] = *(const bf16x8*)(aBase + m * 512);
#pragma unroll
        for (int n = 0; n < 4; ++n) bfr[n] = *(const bf16x8*)(bBase + n * 512);
#pragma unroll
        for (int m = 0; m < 2; ++m)
#pragma unroll
            for (int n = 0; n < 4; ++n)
                acc[m][n] = __builtin_amdgcn_mfma_f32_16x16x32_bf16(af[m], bfr[n], acc[m][n], 0, 0, 0);
        __syncthreads();
    }

    float* Cz = (float*)Cv + ((gridDim.z > 1) ? (long)blockIdx.z * partial_stride : 0L);
#pragma unroll
    for (int m = 0; m < 2; ++m) {
        const int grow0 = m0 + wr * 32 + m * 16 + fq * 4;
#pragma unroll
        for (int n = 0; n < 4; ++n) {
            const int gcol = n0 + wc * 64 + n * 16 + fr;
            float bv = bias ? bias[gcol] : 0.f;
#pragma unroll
            for (int r = 0; r < 4; ++r) {
                long idx = (long)(grow0 + r) * ldc + gcol;
                float v = acc[m][n][r] + bv;
                if (out_bf16) ((bf16_t*)Cv)[idx] = (bf16_t)v;
                else Cz[idx] = v;
            }
        }
    }
}

// ---------------------------------------------------------------- bf16xbf16 batched MFMA GEMM (attention)
__global__ __launch_bounds__(256, 2) void gemm_bb(
    const bf16_t* __restrict__ A, long aO, long aI, int lda,
    const bf16_t* __restrict__ B, long bO, long bI, int ldb,
    void* __restrict__ Cv, long cO, long cI, int ldc,
    int K_len, int out_bf16) {
    __shared__ bf16_t As[128 * 32];
    __shared__ bf16_t Bs[128 * 32];
    const int tid = threadIdx.x;
    const int lane = tid & 63;
    const int wave = tid >> 6;
    const int z = blockIdx.z, zb = z >> 2, zh = z & 3;
    const bf16_t* Az = A + (long)zb * aO + (long)zh * aI;
    const bf16_t* Bz = B + (long)zb * bO + (long)zh * bI;
    const int m0 = blockIdx.y * 128;
    const int n0 = blockIdx.x * 128;

    const int cA = wave * 2;
    const bf16_t* gA0 = Az + (long)(m0 + cA * 16 + (lane >> 2)) * lda + (lane & 3) * 8;
    const bf16_t* gA1 = gA0 + 16L * lda;
    const bf16_t* gB0 = Bz + (long)(n0 + cA * 16 + (lane >> 2)) * ldb + (lane & 3) * 8;
    const bf16_t* gB1 = gB0 + 16L * ldb;
    bf16_t* lA0 = &As[cA * 512];
    bf16_t* lA1 = lA0 + 512;
    bf16_t* lB0 = &Bs[cA * 512];
    bf16_t* lB1 = lB0 + 512;

    const int wr = wave >> 1, wc = wave & 1;
    const int fr = lane & 15, fq = lane >> 4;
    const bf16_t* aBase = &As[(wr * 64 + fr) * 32 + fq * 8];
    const bf16_t* bBase = &Bs[(wc * 64 + fr) * 32 + fq * 8];

    f32x4 acc[4][4] = {};

    for (int kk = 0; kk < K_len; kk += 32) {
        gload_lds16(gA0, lA0);
        gload_lds16(gA1, lA1);
        gload_lds16(gB0, lB0);
        gload_lds16(gB1, lB1);
        gA0 += 32; gA1 += 32; gB0 += 32; gB1 += 32;
        __syncthreads();
        bf16x8 af[4], bfr[4];
#pragma unroll
        for (int m = 0; m < 4; ++m) af[m] = *(const bf16x8*)(aBase + m * 512);
#pragma unroll
        for (int n = 0; n < 4; ++n) bfr[n] = *(const bf16x8*)(bBase + n * 512);
#pragma unroll
        for (int m = 0; m < 4; ++m)
#pragma unroll
            for (int n = 0; n < 4; ++n)
                acc[m][n] = __builtin_amdgcn_mfma_f32_16x16x32_bf16(af[m], bfr[n], acc[m][n], 0, 0, 0);
        __syncthreads();
    }

#pragma unroll
    for (int m = 0; m < 4; ++m) {
        const int grow0 = m0 + wr * 64 + m * 16 + fq * 4;
#pragma unroll
        for (int n = 0; n < 4; ++n) {
            const int gcol = n0 + wc * 64 + n * 16 + fr;
#pragma unroll
            for (int r = 0; r < 4; ++r) {
                long idx = (long)(grow0 + r) * ldc + gcol;
                if (out_bf16) {
                    bf16_t* Cb = (bf16_t*)Cv + (long)zb * cO + (long)zh * cI;
                    Cb[idx] = (bf16_t)acc[m][n][r];
                } else {
                    float* Cf = (float*)Cv + (long)zb * cO + (long)zh * cI;
                    Cf[idx] = acc[m][n][r];
                }
            }
        }
    }
}

// ---------------------------------------------------------------- V transpose (attention)
__global__ void vtrans_kernel(const bf16_t* __restrict__ qkvb, bf16_t* __restrict__ vt) {
    int z = blockIdx.z;  // b*4+h
    int b = z >> 2, h = z & 3;
    int d0 = blockIdx.x * 64, k0 = blockIdx.y * 64;
    __shared__ bf16_t tile[64][72];
    int t = threadIdx.x;  // 256
    int r = t >> 2;
    int c4 = (t & 3) * 16;
    const bf16_t* src = qkvb + ((long)(b * SEQL + k0 + r)) * (3 * D_MODEL) + 2 * D_MODEL +
                        h * HEAD_DIM + d0 + c4;
    bf16x8 v0 = *(const bf16x8*)src;
    bf16x8 v1 = *(const bf16x8*)(src + 8);
#pragma unroll
    for (int j = 0; j < 8; ++j) tile[r][c4 + j] = v0[j];
#pragma unroll
    for (int j = 0; j < 8; ++j) tile[r][c4 + 8 + j] = v1[j];
    __syncthreads();
    int dd = t >> 2, kc = (t & 3) * 16;
    bf16_t* dst = vt + (long)z * (HEAD_DIM * SEQL) + (long)(d0 + dd) * SEQL + k0 + kc;
    bf16x8 o0, o1;
#pragma unroll
    for (int j = 0; j < 8; ++j) o0[j] = tile[kc + j][dd];
#pragma unroll
    for (int j = 0; j < 8; ++j) o1[j] = tile[kc + 8 + j][dd];
    *(bf16x8*)dst = o0;
    *(bf16x8*)(dst + 8) = o1;
}

// ---------------------------------------------------------------- softmax rows of S
__global__ void softmax_kernel(const float* __restrict__ S, bf16_t* __restrict__ P) {
    long row = blockIdx.x;  // 4096 = (b,h,q)
    int tid = threadIdx.x;  // 256
    float s = S[row * SEQL + tid] * 0.044194173824159216f;  // 1/sqrt(512)
    __shared__ float red[4];
    float m = warp_reduce_max(s);
    if ((tid & 63) == 0) red[tid >> 6] = m;
    __syncthreads();
    float gm = fmaxf(fmaxf(red[0], red[1]), fmaxf(red[2], red[3]));
    __syncthreads();
    float p = __expf(s - gm);
    float su = warp_reduce_sum(p);
    if ((tid & 63) == 0) red[tid >> 6] = su;
    __syncthreads();
    float gs = red[0] + red[1] + red[2] + red[3];
    P[row * SEQL + tid] = (bf16_t)(p / gs);
}

// ---------------------------------------------------------------- conv + silu + transpose
__global__ void conv_tr_kernel(const bf16_t* __restrict__ xzb, const float* __restrict__ cw,
                               const float* __restrict__ cb, bf16_t* __restrict__ xT,
                               bf16_t* __restrict__ xcb, bf16_t* __restrict__ zT) {
    __shared__ bf16_t xin[68][64];
    __shared__ bf16_t outt[64][72];  // [e_local][l_local]
    const int e0 = blockIdx.x * 64, l0 = blockIdx.y * 64, b = blockIdx.z;
    const int t = threadIdx.x;
    const int r = t >> 4;            // 0..15
    const int c = (t & 15) * 4;      // 0..60

#pragma unroll
    for (int i = 0; i < 5; ++i) {
        int m = r + i * 16;
        if (m < 67) {
            int l = l0 - 3 + m;
            bf16x4 v;
            if (l >= 0)
                v = *(const bf16x4*)(xzb + ((long)(b * SEQL + l)) * (2 * ED) + e0 + c);
            else {
                v[0] = (bf16_t)0.f; v[1] = (bf16_t)0.f; v[2] = (bf16_t)0.f; v[3] = (bf16_t)0.f;
            }
            *(bf16x4*)&xin[m][c] = v;
        }
    }
    __syncthreads();

    {
        const int e_l = t & 63;
        const int lbase = (t >> 6) * 16;
        const float4 wv = *(const float4*)(cw + (long)(e0 + e_l) * 4);
        const float bias = cb[e0 + e_l];
#pragma unroll
        for (int k = 0; k < 16; ++k) {
            int l = lbase + k;
            float acc = bias + wv.x * (float)xin[l][e_l] + wv.y * (float)xin[l + 1][e_l] +
                        wv.z * (float)xin[l + 2][e_l] + wv.w * (float)xin[l + 3][e_l];
            float s = acc / (1.f + __expf(-acc));
            outt[e_l][l] = (bf16_t)s;
        }
    }
    __syncthreads();

    {
        int er = t >> 2, lc = (t & 3) * 16;
        bf16x8 a = *(bf16x8*)&outt[er][lc];
        bf16x8 bb8 = *(bf16x8*)&outt[er][lc + 8];
        bf16_t* dst = xT + ((long)b * ED + e0 + er) * SEQL + l0 + lc;
        *(bf16x8*)dst = a;
        *(bf16x8*)(dst + 8) = bb8;
    }
    {
        int lr = t >> 2, ec = (t & 3) * 16;
        bf16_t tmp[16];
#pragma unroll
        for (int j = 0; j < 16; ++j) tmp[j] = outt[ec + j][lr];
        bf16_t* dst = xcb + ((long)(b * SEQL + l0 + lr)) * ED + e0 + ec;
        *(bf16x8*)dst = *(bf16x8*)&tmp[0];
        *(bf16x8*)(dst + 8) = *(bf16x8*)&tmp[8];
    }
    __syncthreads();

#pragma unroll
    for (int i = 0; i < 4; ++i) {
        int m = r + i * 16;
        bf16x4 v = *(const bf16x4*)(xzb + ((long)(b * SEQL + l0 + m)) * (2 * ED) + ED + e0 + c);
        *(bf16x4*)&xin[m][c] = v;
    }
    __syncthreads();
    {
        int er = t >> 2, lc = (t & 3) * 16;
        bf16_t tz[16];
#pragma unroll
        for (int j = 0; j < 16; ++j) tz[j] = xin[lc + j][er];
        bf16_t* dst = zT + ((long)b * ED + e0 + er) * SEQL + l0 + lc;
        *(bf16x8*)dst = *(bf16x8*)&tz[0];
        *(bf16x8*)(dst + 8) = *(bf16x8*)&tz[8];
    }
}

// ---------------------------------------------------------------- softplus + transpose
__global__ void softplus_tr_kernel(const float* __restrict__ delta, const float* __restrict__ dt_b,
                                   float* __restrict__ dT) {
    __shared__ float tile[64][65];
    const int e0 = blockIdx.x * 64, l0 = blockIdx.y * 64, b = blockIdx.z;
    const int t = threadIdx.x;
    const int r = t >> 4, c = (t & 15) * 4;
#pragma unroll
    for (int i = 0; i < 4; ++i) {
        int l = r + i * 16;
        float4 v = *(const float4*)(delta + ((long)(b * SEQL + l0 + l)) * ED + e0 + c);
        float4 bb = *(const float4*)(dt_b + e0 + c);
        float u0 = v.x + bb.x, u1 = v.y + bb.y, u2 = v.z + bb.z, u3 = v.w + bb.w;
        tile[l][c] = (u0 > 20.f) ? u0 : log1pf(__expf(u0));
        tile[l][c + 1] = (u1 > 20.f) ? u1 : log1pf(__expf(u1));
        tile[l][c + 2] = (u2 > 20.f) ? u2 : log1pf(__expf(u2));
        tile[l][c + 3] = (u3 > 20.f) ? u3 : log1pf(__expf(u3));
    }
    __syncthreads();
#pragma unroll
    for (int i = 0; i < 4; ++i) {
        int ee = r + i * 16;
        float4 w;
        w.x = tile[c][ee];
        w.y = tile[c + 1][ee];
        w.z = tile[c + 2][ee];
        w.w = tile[c + 3][ee];
        *(float4*)(dT + ((long)b * ED + e0 + ee) * SEQL + l0 + c) = w;
    }
}

// ---------------------------------------------------------------- chunk-parallel selective scan
__global__ __launch_bounds__(256) void scan_chunk_kernel(
    const float* __restrict__ dT, const bf16_t* __restrict__ xT, const bf16_t* __restrict__ zT,
    const float* __restrict__ dbc, const float* __restrict__ A_log, const float* __restrict__ Dp,
    bf16_t* __restrict__ yT) {
    __shared__ float bc[SEQL][36];  // permuted rows; cols 0..15 = B, 16..31 = C
    const int t = threadIdx.x;
    const int chunk = t & 15;
    const int el = t >> 4;
    const int b = blockIdx.y;
    const int e = blockIdx.x * 16 + el;
    const int l0 = chunk * 16;
    const int R = DT_RANK + 2 * D_STATE;  // 160

    {
        const int row0 = t >> 3;
        const int col = (t & 7) * 4;
        const float* src = dbc + (long)b * SEQL * R + DT_RANK;
#pragma unroll
        for (int it = 0; it < 8; ++it) {
            int row = row0 + it * 32;
            int prow = ((row & 15) << 4) | (row >> 4);
            *(float4*)&bc[prow][col] = *(const float4*)(src + (long)row * R + col);
        }
    }

    float Ar[16];
    {
        const float* ap = A_log + (long)e * D_STATE;
#pragma unroll
        for (int n = 0; n < 16; n += 4) {
            float4 v = *(const float4*)(ap + n);
            Ar[n] = -__expf(v.x);
            Ar[n + 1] = -__expf(v.y);
            Ar[n + 2] = -__expf(v.z);
            Ar[n + 3] = -__expf(v.w);
        }
    }
    float d[16];
    {
        const float* dp = dT + ((long)b * ED + e) * SEQL + l0;
#pragma unroll
        for (int j = 0; j < 16; j += 4) *(float4*)&d[j] = *(const float4*)(dp + j);
    }
    float xf[16];
    {
        const bf16_t* xp = xT + ((long)b * ED + e) * SEQL + l0;
        bf16x8 x0 = *(const bf16x8*)xp;
        bf16x8 x1 = *(const bf16x8*)(xp + 8);
#pragma unroll
        for (int j = 0; j < 8; ++j) {
            xf[j] = (float)x0[j];
            xf[8 + j] = (float)x1[j];
        }
    }
    __syncthreads();

    float P[16], S[16];
#pragma unroll
    for (int n = 0; n < 16; ++n) {
        P[n] = 1.f;
        S[n] = 0.f;
    }

#pragma unroll
    for (int j = 0; j < 16; ++j) {
        const float* br = &bc[(j << 4) | chunk][0];
        float dj = d[j];
        float dx = dj * xf[j];
#pragma unroll
        for (int n = 0; n < 16; ++n) {
            float dA = __expf(dj * Ar[n]);
            S[n] = dA * S[n] + dx * br[n];
            P[n] *= dA;
        }
    }

#pragma unroll
    for (int off = 1; off < 16; off <<= 1) {
        float Pp[16], Sp[16];
#pragma unroll
        for (int n = 0; n < 16; ++n) {
            Pp[n] = __shfl_up(P[n], off, 16);
            Sp[n] = __shfl_up(S[n], off, 16);
        }
        if (chunk >= off) {
#pragma unroll
            for (int n = 0; n < 16; ++n) {
                S[n] = P[n] * Sp[n] + S[n];
                P[n] *= Pp[n];
            }
        }
    }

    float h[16];
#pragma unroll
    for (int n = 0; n < 16; ++n) {
        float hs = __shfl_up(S[n], 1, 16);
        h[n] = (chunk == 0) ? 0.f : hs;
    }

    const float dpe = Dp[e];
    float yf[16];
#pragma unroll
    for (int j = 0; j < 16; ++j) {
        const float* br = &bc[(j << 4) | chunk][0];
        float dj = d[j];
        float dx = dj * xf[j];
        float y = 0.f;
#pragma unroll
        for (int n = 0; n < 16; ++n) {
            float dA = __expf(dj * Ar[n]);
            h[n] = dA * h[n] + dx * br[n];
            y += h[n] * br[16 + n];
        }
        yf[j] = y + xf[j] * dpe;
    }

    const bf16_t* zp = zT + ((long)b * ED + e) * SEQL + l0;
    bf16_t* yp = yT + ((long)b * ED + e) * SEQL + l0;
    {
        bf16x8 z0 = *(const bf16x8*)zp;
        bf16x8 o0;
#pragma unroll
        for (int j = 0; j < 8; ++j) {
            float z = (float)z0[j];
            o0[j] = (bf16_t)(yf[j] * (z / (1.f + __expf(-z))));
        }
        *(bf16x8*)yp = o0;
        bf16x8 z1 = *(const bf16x8*)(zp + 8);
        bf16x8 o1;
#pragma unroll
        for (int j = 0; j < 8; ++j) {
            float z = (float)z1[j];
            o1[j] = (bf16_t)(yf[8 + j] * (z / (1.f + __expf(-z))));
        }
        *(bf16x8*)(yp + 8) = o1;
    }
}

// ---------------------------------------------------------------- yT [B][ED][L] -> Y [B*L][ED]
__global__ void ytr_kernel(const bf16_t* __restrict__ yT, bf16_t* __restrict__ Y) {
    __shared__ bf16_t tl[64][72];
    const int e0 = blockIdx.x * 64, l0 = blockIdx.y * 64, b = blockIdx.z;
    const int t = threadIdx.x;
    {
        int er = t >> 2, lc = (t & 3) * 16;
        const bf16_t* src = yT + ((long)b * ED + e0 + er) * SEQL + l0 + lc;
        bf16x8 a = *(const bf16x8*)src;
        bf16x8 bb8 = *(const bf16x8*)(src + 8);
        *(bf16x8*)&tl[er][lc] = a;
        *(bf16x8*)&tl[er][lc + 8] = bb8;
    }
    __syncthreads();
    {
        int lr = t >> 2, ec = (t & 3) * 16;
        bf16_t tmp[16];
#pragma unroll
        for (int j = 0; j < 16; ++j) tmp[j] = tl[ec + j][lr];
        bf16_t* dst = Y + ((long)(b * SEQL + l0 + lr)) * ED + e0 + ec;
        *(bf16x8*)dst = *(bf16x8*)&tmp[0];
        *(bf16x8*)(dst + 8) = *(bf16x8*)&tmp[8];
    }
}

// ---------------------------------------------------------------- head GEMV1
__global__ void head_gemv1(const float* __restrict__ H, const float* __restrict__ w1,
                           const float* __restrict__ b1, float* __restrict__ hm1) {
    int b = blockIdx.y;
    int wave = threadIdx.x >> 6, lane = threadIdx.x & 63;
    int n = blockIdx.x * 4 + wave;
    const float* last = H + ((long)(b * SEQL + SEQL - 1)) * D_MODEL;
    const float* wr = w1 + (long)n * D_MODEL;
    float s = 0.f;
    for (int j = lane * 4; j < D_MODEL; j += 256) {
        float4 a = *(const float4*)(last + j);
        float4 w = *(const float4*)(wr + j);
        s += a.x * w.x + a.y * w.y + a.z * w.z + a.w * w.w;
    }
    s = warp_reduce_sum(s);
    if (lane == 0) hm1[b * 1024 + n] = s + b1[n];
}

// ---------------------------------------------------------------- head final
__global__ void head_final(const float* __restrict__ hm1, const float* __restrict__ ln_g,
                           const float* __restrict__ ln_b, const float* __restrict__ w2,
                           const float* __restrict__ b2, float* __restrict__ out) {
    int b = blockIdx.x;
    int tid = threadIdx.x;  // 1024
    __shared__ float hm[1024];
    __shared__ float r1[16], r2[16];
    __shared__ float stats[2];
    __shared__ float outs[64];

    float v = hm1[b * 1024 + tid];
    float s1 = warp_reduce_sum(v);
    float s2 = warp_reduce_sum(v * v);
    int wave = tid >> 6;
    if ((tid & 63) == 0) { r1[wave] = s1; r2[wave] = s2; }
    __syncthreads();
    if (tid == 0) {
        float t1 = 0.f, t2 = 0.f;
        for (int w = 0; w < 16; ++w) { t1 += r1[w]; t2 += r2[w]; }
        float mean = t1 / 1024.f;
        stats[0] = mean;
        stats[1] = rsqrtf(t2 / 1024.f - mean * mean + 1e-5f);
    }
    __syncthreads();
    float x = (v - stats[0]) * stats[1] * ln_g[tid] + ln_b[tid];
    x = (x > 0.f) ? x : (__expf(x) - 1.f);
    hm[tid] = x;
    __syncthreads();

    int o = tid >> 4, kk = tid & 15;
    float a = 0.f;
    const float* w2r = w2 + (long)o * 1024;
    for (int j = kk; j < 1024; j += 16) a += hm[j] * w2r[j];
#pragma unroll
    for (int off = 1; off < 16; off <<= 1) a += __shfl_xor(a, off);
    if (kk == 0) outs[o] = a + b2[o];
    __syncthreads();
    if (tid < 64) {
        float vv = outs[tid];
        float ss = warp_reduce_sum(vv * vv);
        out[b * 64 + tid] = vv / fmaxf(sqrtf(ss), 1e-12f);
    }
}

// ---------------------------------------------------------------- launch
extern "C" void kernel_launch(void* const* d_in, const int* in_sizes, int n_in,
                              void* d_out, int out_size, void* d_ws, size_t ws_size,
                              hipStream_t stream) {
    const float* x = (const float*)d_in[0];
    const float* norm_w = (const float*)d_in[1];
    const float* in_proj_w = (const float*)d_in[2];
    const float* conv_w = (const float*)d_in[3];
    const float* conv_b = (const float*)d_in[4];
    const float* x_proj_w = (const float*)d_in[5];
    const float* dt_proj_w = (const float*)d_in[6];
    const float* dt_proj_b = (const float*)d_in[7];
    const float* A_log = (const float*)d_in[8];
    const float* D_param = (const float*)d_in[9];
    const float* out_proj_w = (const float*)d_in[10];
    const float* attn_in_w = (const float*)d_in[11];
    const float* attn_in_b = (const float*)d_in[12];
    const float* attn_out_w = (const float*)d_in[13];
    const float* attn_out_b = (const float*)d_in[14];
    const float* w1 = (const float*)d_in[15];
    const float* b1 = (const float*)d_in[16];
    const float* ln_g = (const float*)d_in[17];
    const float* ln_b = (const float*)d_in[18];
    const float* w2 = (const float*)d_in[19];
    const float* b2 = (const float*)d_in[20];

    float* ws = (float*)d_ws;
    // ---- workspace layout (floats). XNb moved before DELTA so the dead region
    // DELTA..Yb-head is contiguous for the in_proj bf16-weight buffer.
    float* H = ws;                                    // @0        2097152
    float* SCR = ws + 2097152;                        // @2097152  6291456
    bf16_t* XNb = (bf16_t*)(ws + 8388608);            // @8388608  1048576
    float* DELTA = ws + 9437184;                      // @9437184  4194304
    float* DBC = ws + 13631488;                       // @13631488 163840
    float* XPART = ws + 13795328;                     // @13795328 1310720
    bf16_t* XCb = (bf16_t*)(ws + 15106048);           // @15106048 2097152
    bf16_t* DTb = (bf16_t*)(ws + 17203200);           // @17203200 65536
    bf16_t* Yb = (bf16_t*)(ws + 17268736);            // @17268736 2097152
    bf16_t* Hb = (bf16_t*)(ws + 19365888);            // @19365888 1048576
    bf16_t* AOb = (bf16_t*)(ws + 20414464);           // @20414464 1048576
    float* HM1 = ws + 21463040;                       // @21463040 4096
    bf16_t* XT = (bf16_t*)(ws + 21467136);            // @21467136 2097152
    bf16_t* ZT = (bf16_t*)(ws + 23564288);            // @23564288 2097152
    // total 25661440 floats = 102.6 MB

    // weight bf16 staging buffers (all in dead-at-time regions, audited):
    bf16_t* WBin = (bf16_t*)(ws + 9437184);   // in_proj: 16.8M elem, spans DELTA..Yb head (dead pre-conv)
    bf16_t* WBout = (bf16_t*)(ws + 21467136); // out_proj: 8.4M elem = XT+ZT (dead post-scan)
    bf16_t* WBai = (bf16_t*)(ws + 8388608);   // attn_in: 12.6M elem, spans XNb..XCb head (dead in attn)
    bf16_t* WBao = (bf16_t*)(ws + 21467136);  // attn_out: 4.2M elem = XT (dead in attn)

    bf16_t* XZb = (bf16_t*)SCR;                       // [B*L][2ED] bf16 (dead after conv_tr)
    float* DTT = SCR;                                 // [B][ED][L] f32 (after XZb dead)
    bf16_t* YTT = (bf16_t*)(SCR + 4194304);           // [B][ED][L] bf16
    float* PART = SCR;                                // splitK partials: SCR+XNb+DELTA-head (8.4M floats)

    bf16_t* QKVb = (bf16_t*)SCR;                      // attention phase
    float* SBUF = SCR + 3145728;
    bf16_t* Pb = (bf16_t*)(SCR + 3145728 + 1048576);
    bf16_t* VTb = (bf16_t*)(SCR + 3145728 + 1048576 + 524288);

    const int M = BATCH * SEQL;  // 1024
    const long S_H = (long)M * D_MODEL;

    copy_kernel<<<(S_H + 255) / 256, 256, 0, stream>>>(x, H, (int)S_H);

    for (int i = 0; i < N_LAYERS; ++i) {
        rmsnorm_kernel<<<M, 256, 0, stream>>>(H, norm_w + (long)i * D_MODEL, XNb);
        // in_proj: convert weights to bf16, then 64x128-tile bf16xbf16 GEMM (1024 blocks)
        f2b8_kernel<<<8192, 256, 0, stream>>>(in_proj_w + (long)i * 2 * ED * D_MODEL, WBin,
                                              (long)2 * ED * D_MODEL / 8);
        gemm_w64<<<dim3(64, 16, 1), 256, 0, stream>>>(XNb, D_MODEL, WBin, D_MODEL, XZb, 2 * ED,
                                                      D_MODEL, nullptr, 1, 0);
        conv_tr_kernel<<<dim3(64, 4, 4), 256, 0, stream>>>(
            XZb, conv_w + (long)i * ED * D_CONV, conv_b + (long)i * ED, XT, XCb, ZT);
        gemm_bf16<<<dim3(2, 8, 8), 256, 0, stream>>>(
            XCb, ED, x_proj_w + (long)i * (DT_RANK + 2 * D_STATE) * ED, ED, XPART,
            DT_RANK + 2 * D_STATE, DT_RANK + 2 * D_STATE, ED / 8, nullptr, 0, 0,
            (long)M * (DT_RANK + 2 * D_STATE));
        ksum_kernel<<<640, 256, 0, stream>>>(XPART, DBC, M * (DT_RANK + 2 * D_STATE), 8,
                                             (long)M * (DT_RANK + 2 * D_STATE));
        dt_pack_kernel<<<512, 256, 0, stream>>>(DBC, DTb);
        gemm_bf16<<<dim3(32, 8, 1), 256, 0, stream>>>(
            DTb, DT_RANK, dt_proj_w + (long)i * ED * DT_RANK, DT_RANK, DELTA, ED, ED, DT_RANK,
            nullptr, 0, 0, 0);
        softplus_tr_kernel<<<dim3(64, 4, 4), 256, 0, stream>>>(DELTA, dt_proj_b + (long)i * ED,
                                                               DTT);
        scan_chunk_kernel<<<dim3(ED / 16, BATCH), 256, 0, stream>>>(
            DTT, XT, ZT, DBC, A_log + (long)i * ED * D_STATE, D_param + (long)i * ED, YTT);
        ytr_kernel<<<dim3(64, 4, 4), 256, 0, stream>>>(YTT, Yb);
        // out_proj: bf16 weights into XT/ZT (dead post-scan), split-K=4 -> PART, add into H
        f2b8_kernel<<<4096, 256, 0, stream>>>(out_proj_w + (long)i * D_MODEL * ED, WBout,
                                              (long)D_MODEL * ED / 8);
        gemm_w64<<<dim3(16, 16, 4), 256, 0, stream>>>(Yb, ED, WBout, ED, PART, D_MODEL, ED / 4,
                                                      nullptr, 0, (long)M * D_MODEL);
        ksum_add_kernel<<<8192, 256, 0, stream>>>(PART, H, M * D_MODEL, 4, (long)M * D_MODEL,
                                                  nullptr, 0);
    }

    f2b_kernel<<<(int)((S_H + 255) / 256), 256, 0, stream>>>(H, Hb, (int)S_H);
    // attn_in: bf16 weights into XNb..XCb-head region (dead in attn phase)
    f2b8_kernel<<<6144, 256, 0, stream>>>(attn_in_w, WBai, (long)3 * D_MODEL * D_MODEL / 8);
    gemm_w64<<<dim3(48, 16, 1), 256, 0, stream>>>(Hb, D_MODEL, WBai, D_MODEL, QKVb, 3 * D_MODEL,
                                                  D_MODEL, attn_in_b, 1, 0);
    vtrans_kernel<<<dim3(8, 4, 16), 256, 0, stream>>>(QKVb, VTb);
    gemm_bb<<<dim3(2, 2, 16), 256, 0, stream>>>(
        QKVb, (long)SEQL * 3 * D_MODEL, HEAD_DIM, 3 * D_MODEL,
        QKVb + D_MODEL, (long)SEQL * 3 * D_MODEL, HEAD_DIM, 3 * D_MODEL,
        SBUF, 4L * SEQL * SEQL, (long)SEQL * SEQL, SEQL, HEAD_DIM, 0);
    softmax_kernel<<<BATCH * N_HEADS * SEQL, 256, 0, stream>>>(SBUF, Pb);
    gemm_bb<<<dim3(4, 2, 16), 256, 0, stream>>>(
        Pb, 4L * SEQL * SEQL, (long)SEQL * SEQL, SEQL,
        VTb, 4L * HEAD_DIM * SEQL, (long)HEAD_DIM * SEQL, SEQL,
        AOb, (long)SEQL * D_MODEL, HEAD_DIM, D_MODEL, SEQL, 1);
    // attn_out: bf16 weights into XT (dead), split-K=4; bias folded into the reduce
    f2b8_kernel<<<2048, 256, 0, stream>>>(attn_out_w, WBao, (long)D_MODEL * D_MODEL / 8);
    gemm_w64<<<dim3(16, 16, 4), 256, 0, stream>>>(AOb, D_MODEL, WBao, D_MODEL, PART, D_MODEL,
                                                  D_MODEL / 4, nullptr, 0, (long)M * D_MODEL);
    ksum_add_kernel<<<8192, 256, 0, stream>>>(PART, H, M * D_MODEL, 4, (long)M * D_MODEL,
                                              attn_out_b, D_MODEL - 1);

    head_gemv1<<<dim3(256, 4), 256, 0, stream>>>(H, w1, b1, HM1);
    head_final<<<BATCH, 1024, 0, stream>>>(HM1, ln_g, ln_b, w2, b2, (float*)d_out);
}

// Round 10
// 662.517 us; speedup vs baseline: 1.3367x; 1.0224x over previous
//
#include <hip/hip_runtime.h>
#include <hip/hip_bf16.h>
#include <math.h>

#define D_MODEL 2048
#define N_LAYERS 2
#define ED 4096
#define D_STATE 16
#define D_CONV 4
#define DT_RANK 128
#define N_HEADS 4
#define HEAD_DIM 512
#define BATCH 4
#define SEQL 256

typedef __bf16 bf16_t;
typedef bf16_t bf16x8 __attribute__((ext_vector_type(8)));
typedef bf16_t bf16x4 __attribute__((ext_vector_type(4)));
typedef float f32x4 __attribute__((ext_vector_type(4)));

// ---------------------------------------------------------------- utilities
__device__ __forceinline__ float warp_reduce_sum(float v) {
#pragma unroll
    for (int off = 1; off < 64; off <<= 1) v += __shfl_xor(v, off);
    return v;
}
__device__ __forceinline__ float warp_reduce_max(float v) {
#pragma unroll
    for (int off = 1; off < 64; off <<= 1) v = fmaxf(v, __shfl_xor(v, off));
    return v;
}

__device__ __forceinline__ void gload_lds16(const bf16_t* g, bf16_t* l) {
    __builtin_amdgcn_global_load_lds(
        (const __attribute__((address_space(1))) unsigned int*)g,
        (__attribute__((address_space(3))) unsigned int*)l, 16, 0, 0);
}

// ---------------------------------------------------------------- copy / convert
__global__ void copy4_kernel(const float4* __restrict__ src, float4* __restrict__ dst, int n4) {
    int i = blockIdx.x * blockDim.x + threadIdx.x;
    if (i < n4) dst[i] = src[i];
}

// vectorized fp32 -> bf16 (8 per thread)
__global__ void f2b8_kernel(const float* __restrict__ src, bf16_t* __restrict__ dst, long n8) {
    long i = (long)blockIdx.x * blockDim.x + threadIdx.x;
    if (i >= n8) return;
    float4 a = ((const float4*)src)[2 * i];
    float4 b = ((const float4*)src)[2 * i + 1];
    bf16x8 o;
    o[0] = (bf16_t)a.x; o[1] = (bf16_t)a.y; o[2] = (bf16_t)a.z; o[3] = (bf16_t)a.w;
    o[4] = (bf16_t)b.x; o[5] = (bf16_t)b.y; o[6] = (bf16_t)b.z; o[7] = (bf16_t)b.w;
    ((bf16x8*)dst)[i] = o;
}

// sum split-K partials -> out (fp32) AND pack dt columns (col<128) -> dtb (bf16)
__global__ void ksum_dt_kernel(const float* __restrict__ part, float* __restrict__ out,
                               bf16_t* __restrict__ dtb, int n, int nz, long stride) {
    int i = blockIdx.x * blockDim.x + threadIdx.x;
    if (i >= n) return;
    float s = 0.f;
    for (int z = 0; z < nz; ++z) s += part[(long)z * stride + i];
    out[i] = s;
    int row = i / 160;
    int col = i - row * 160;
    if (col < DT_RANK) dtb[row * DT_RANK + col] = (bf16_t)s;
}

__global__ void ksum_add_kernel(const float* __restrict__ part, float* __restrict__ out, int n,
                                int nz, long stride, const float* __restrict__ bias, int bmask) {
    int i = blockIdx.x * blockDim.x + threadIdx.x;
    if (i >= n) return;
    float s = out[i];
    for (int z = 0; z < nz; ++z) s += part[(long)z * stride + i];
    if (bias) s += bias[i & bmask];
    out[i] = s;
}

// ---------------------------------------------------------------- rmsnorm (bf16 out)
__global__ void rmsnorm_kernel(const float* __restrict__ x, const float* __restrict__ w,
                               bf16_t* __restrict__ o) {
    int row = blockIdx.x;
    int tid = threadIdx.x;  // 256
    const float* xr = x + (long)row * D_MODEL;
    float ss = 0.f;
    for (int i = tid; i < D_MODEL; i += 256) { float v = xr[i]; ss += v * v; }
    ss = warp_reduce_sum(ss);
    __shared__ float r[4];
    int wave = tid >> 6;
    if ((tid & 63) == 0) r[wave] = ss;
    __syncthreads();
    float tot = r[0] + r[1] + r[2] + r[3];
    float sc = rsqrtf(tot / (float)D_MODEL + 1e-5f);
    bf16_t* orow = o + (long)row * D_MODEL;
    for (int i = tid; i < D_MODEL; i += 256) orow[i] = (bf16_t)(xr[i] * sc * w[i]);
}

// ---------------------------------------------------------------- bf16 MFMA GEMM (fp32 B weights)
// out_mode: 0 = fp32 C (split-K partials ok), 2 = softplus(acc+bias) transposed into dT[b][e][l]
__global__ __launch_bounds__(256, 2) void gemm_bf16(
    const bf16_t* __restrict__ A, int lda, const float* __restrict__ B, int ldb,
    float* __restrict__ C, int ldc, int N, int K_len, const float* __restrict__ bias,
    int out_mode, long partial_stride) {
    __shared__ bf16_t As[128 * 32];
    __shared__ bf16_t Bs[128 * 32];
    const int tid = threadIdx.x;
    const int lane = tid & 63;
    const int wave = tid >> 6;
    const int m0 = blockIdx.y * 128;
    const int n0 = blockIdx.x * 128;
    const int kbeg = blockIdx.z * K_len;

    const int cA = wave * 2;
    const bf16_t* gA0 = A + (long)(m0 + cA * 16 + (lane >> 2)) * lda + kbeg + (lane & 3) * 8;
    const bf16_t* gA1 = gA0 + 16L * lda;
    bf16_t* lA0 = &As[cA * 512];
    bf16_t* lA1 = &As[cA * 512 + 512];

    const int brow = tid >> 1;
    const int bcol = (tid & 1) * 16;
    const bool bvalid = (n0 + brow) < N;
    const float* gB = B + (long)(n0 + brow) * ldb + kbeg + bcol;
    bf16_t* lB = &Bs[brow * 32 + bcol];

    const int wr = wave >> 1, wc = wave & 1;
    const int fr = lane & 15, fq = lane >> 4;
    const bf16_t* aBase = &As[(wr * 64 + fr) * 32 + fq * 8];
    const bf16_t* bBase = &Bs[(wc * 64 + fr) * 32 + fq * 8];

    f32x4 acc[4][4] = {};

    for (int kk = 0; kk < K_len; kk += 32) {
        gload_lds16(gA0, lA0);
        gload_lds16(gA1, lA1);
        gA0 += 32;
        gA1 += 32;
        if (bvalid) {
            float4 v0 = *(const float4*)(gB);
            float4 v1 = *(const float4*)(gB + 4);
            float4 v2 = *(const float4*)(gB + 8);
            float4 v3 = *(const float4*)(gB + 12);
            gB += 32;
            bf16x8 p0, p1;
            p0[0] = (bf16_t)v0.x; p0[1] = (bf16_t)v0.y; p0[2] = (bf16_t)v0.z; p0[3] = (bf16_t)v0.w;
            p0[4] = (bf16_t)v1.x; p0[5] = (bf16_t)v1.y; p0[6] = (bf16_t)v1.z; p0[7] = (bf16_t)v1.w;
            p1[0] = (bf16_t)v2.x; p1[1] = (bf16_t)v2.y; p1[2] = (bf16_t)v2.z; p1[3] = (bf16_t)v2.w;
            p1[4] = (bf16_t)v3.x; p1[5] = (bf16_t)v3.y; p1[6] = (bf16_t)v3.z; p1[7] = (bf16_t)v3.w;
            *(bf16x8*)lB = p0;
            *((bf16x8*)lB + 1) = p1;
        }
        __syncthreads();
        bf16x8 af[4], bfr[4];
#pragma unroll
        for (int m = 0; m < 4; ++m) af[m] = *(const bf16x8*)(aBase + m * 512);
#pragma unroll
        for (int n = 0; n < 4; ++n) bfr[n] = *(const bf16x8*)(bBase + n * 512);
#pragma unroll
        for (int m = 0; m < 4; ++m)
#pragma unroll
            for (int n = 0; n < 4; ++n)
                acc[m][n] = __builtin_amdgcn_mfma_f32_16x16x32_bf16(af[m], bfr[n], acc[m][n], 0, 0, 0);
        __syncthreads();
    }

    if (out_mode == 2) {
        // dt path: v = softplus(acc + bias[gcol]); write transposed to dT[b][e][l]
#pragma unroll
        for (int m = 0; m < 4; ++m) {
            const int grow0 = m0 + wr * 64 + m * 16 + fq * 4;
            const int bb = grow0 >> 8;
            const int l = grow0 & 255;
#pragma unroll
            for (int n = 0; n < 4; ++n) {
                const int gcol = n0 + wc * 64 + n * 16 + fr;
                const float bv = bias[gcol];
                float4 w;
                float u;
                u = acc[m][n][0] + bv; w.x = (u > 20.f) ? u : log1pf(__expf(u));
                u = acc[m][n][1] + bv; w.y = (u > 20.f) ? u : log1pf(__expf(u));
                u = acc[m][n][2] + bv; w.z = (u > 20.f) ? u : log1pf(__expf(u));
                u = acc[m][n][3] + bv; w.w = (u > 20.f) ? u : log1pf(__expf(u));
                *(float4*)(C + ((long)bb * ED + gcol) * SEQL + l) = w;
            }
        }
        return;
    }

    float* Cz = C + ((gridDim.z > 1) ? (long)blockIdx.z * partial_stride : 0L);
#pragma unroll
    for (int m = 0; m < 4; ++m) {
        const int grow0 = m0 + wr * 64 + m * 16 + fq * 4;
#pragma unroll
        for (int n = 0; n < 4; ++n) {
            const int gcol = n0 + wc * 64 + n * 16 + fr;
            if (gcol >= N) continue;
            float bv = bias ? bias[gcol] : 0.f;
#pragma unroll
            for (int r = 0; r < 4; ++r) {
                long idx = (long)(grow0 + r) * ldc + gcol;
                Cz[idx] = acc[m][n][r] + bv;
            }
        }
    }
}

// ---------------------------------------------------------------- bf16 x bf16 weight GEMM, BM=64
__global__ __launch_bounds__(256, 4) void gemm_w64(
    const bf16_t* __restrict__ A, int lda, const bf16_t* __restrict__ B, int ldb,
    void* __restrict__ Cv, int ldc, int K_len, const float* __restrict__ bias,
    int out_bf16, long partial_stride) {
    __shared__ bf16_t As[64 * 32];
    __shared__ bf16_t Bs[128 * 32];
    const int tid = threadIdx.x;
    const int lane = tid & 63;
    const int wave = tid >> 6;
    const int m0 = blockIdx.y * 64;
    const int n0 = blockIdx.x * 128;
    const int kbeg = blockIdx.z * K_len;

    const bf16_t* gA = A + (long)(m0 + wave * 16 + (lane >> 2)) * lda + kbeg + (lane & 3) * 8;
    bf16_t* lA = &As[wave * 512];
    const bf16_t* gB0 = B + (long)(n0 + wave * 32 + (lane >> 2)) * ldb + kbeg + (lane & 3) * 8;
    const bf16_t* gB1 = gB0 + 16L * ldb;
    bf16_t* lB0 = &Bs[wave * 1024];
    bf16_t* lB1 = lB0 + 512;

    const int wr = wave >> 1, wc = wave & 1;
    const int fr = lane & 15, fq = lane >> 4;
    const bf16_t* aBase = &As[(wr * 32 + fr) * 32 + fq * 8];
    const bf16_t* bBase = &Bs[(wc * 64 + fr) * 32 + fq * 8];

    f32x4 acc[2][4] = {};

    for (int kk = 0; kk < K_len; kk += 32) {
        gload_lds16(gA, lA);
        gload_lds16(gB0, lB0);
        gload_lds16(gB1, lB1);
        gA += 32; gB0 += 32; gB1 += 32;
        __syncthreads();
        bf16x8 af[2], bfr[4];
#pragma unroll
        for (int m = 0; m < 2; ++m) af[m] = *(const bf16x8*)(aBase + m * 512);
#pragma unroll
        for (int n = 0; n < 4; ++n) bfr[n] = *(const bf16x8*)(bBase + n * 512);
#pragma unroll
        for (int m = 0; m < 2; ++m)
#pragma unroll
            for (int n = 0; n < 4; ++n)
                acc[m][n] = __builtin_amdgcn_mfma_f32_16x16x32_bf16(af[m], bfr[n], acc[m][n], 0, 0, 0);
        __syncthreads();
    }

    float* Cz = (float*)Cv + ((gridDim.z > 1) ? (long)blockIdx.z * partial_stride : 0L);
#pragma unroll
    for (int m = 0; m < 2; ++m) {
        const int grow0 = m0 + wr * 32 + m * 16 + fq * 4;
#pragma unroll
        for (int n = 0; n < 4; ++n) {
            const int gcol = n0 + wc * 64 + n * 16 + fr;
            float bv = bias ? bias[gcol] : 0.f;
#pragma unroll
            for (int r = 0; r < 4; ++r) {
                long idx = (long)(grow0 + r) * ldc + gcol;
                float v = acc[m][n][r] + bv;
                if (out_bf16) ((bf16_t*)Cv)[idx] = (bf16_t)v;
                else Cz[idx] = v;
            }
        }
    }
}

// ---------------------------------------------------------------- batched bf16xbf16 GEMM, BM=64
// per z: C = A * B^T ; offsets (z>>2)*Outer + (z&3)*Inner
__global__ __launch_bounds__(256, 4) void gemm_bb64(
    const bf16_t* __restrict__ A, long aO, long aI, int lda,
    const bf16_t* __restrict__ B, long bO, long bI, int ldb,
    void* __restrict__ Cv, long cO, long cI, int ldc,
    int K_len, int out_bf16) {
    __shared__ bf16_t As[64 * 32];
    __shared__ bf16_t Bs[128 * 32];
    const int tid = threadIdx.x;
    const int lane = tid & 63;
    const int wave = tid >> 6;
    const int z = blockIdx.z, zb = z >> 2, zh = z & 3;
    const bf16_t* Az = A + (long)zb * aO + (long)zh * aI;
    const bf16_t* Bz = B + (long)zb * bO + (long)zh * bI;
    const int m0 = blockIdx.y * 64;
    const int n0 = blockIdx.x * 128;

    const bf16_t* gA = Az + (long)(m0 + wave * 16 + (lane >> 2)) * lda + (lane & 3) * 8;
    bf16_t* lA = &As[wave * 512];
    const bf16_t* gB0 = Bz + (long)(n0 + wave * 32 + (lane >> 2)) * ldb + (lane & 3) * 8;
    const bf16_t* gB1 = gB0 + 16L * ldb;
    bf16_t* lB0 = &Bs[wave * 1024];
    bf16_t* lB1 = lB0 + 512;

    const int wr = wave >> 1, wc = wave & 1;
    const int fr = lane & 15, fq = lane >> 4;
    const bf16_t* aBase = &As[(wr * 32 + fr) * 32 + fq * 8];
    const bf16_t* bBase = &Bs[(wc * 64 + fr) * 32 + fq * 8];

    f32x4 acc[2][4] = {};

    for (int kk = 0; kk < K_len; kk += 32) {
        gload_lds16(gA, lA);
        gload_lds16(gB0, lB0);
        gload_lds16(gB1, lB1);
        gA += 32; gB0 += 32; gB1 += 32;
        __syncthreads();
        bf16x8 af[2], bfr[4];
#pragma unroll
        for (int m = 0; m < 2; ++m) af[m] = *(const bf16x8*)(aBase + m * 512);
#pragma unroll
        for (int n = 0; n < 4; ++n) bfr[n] = *(const bf16x8*)(bBase + n * 512);
#pragma unroll
        for (int m = 0; m < 2; ++m)
#pragma unroll
            for (int n = 0; n < 4; ++n)
                acc[m][n] = __builtin_amdgcn_mfma_f32_16x16x32_bf16(af[m], bfr[n], acc[m][n], 0, 0, 0);
        __syncthreads();
    }

#pragma unroll
    for (int m = 0; m < 2; ++m) {
        const int grow0 = m0 + wr * 32 + m * 16 + fq * 4;
#pragma unroll
        for (int n = 0; n < 4; ++n) {
            const int gcol = n0 + wc * 64 + n * 16 + fr;
#pragma unroll
            for (int r = 0; r < 4; ++r) {
                long idx = (long)(grow0 + r) * ldc + gcol;
                if (out_bf16) {
                    bf16_t* Cb = (bf16_t*)Cv + (long)zb * cO + (long)zh * cI;
                    Cb[idx] = (bf16_t)acc[m][n][r];
                } else {
                    float* Cf = (float*)Cv + (long)zb * cO + (long)zh * cI;
                    Cf[idx] = acc[m][n][r];
                }
            }
        }
    }
}

// ---------------------------------------------------------------- V transpose (attention)
__global__ void vtrans_kernel(const bf16_t* __restrict__ qkvb, bf16_t* __restrict__ vt) {
    int z = blockIdx.z;  // b*4+h
    int b = z >> 2, h = z & 3;
    int d0 = blockIdx.x * 64, k0 = blockIdx.y * 64;
    __shared__ bf16_t tile[64][72];
    int t = threadIdx.x;  // 256
    int r = t >> 2;
    int c4 = (t & 3) * 16;
    const bf16_t* src = qkvb + ((long)(b * SEQL + k0 + r)) * (3 * D_MODEL) + 2 * D_MODEL +
                        h * HEAD_DIM + d0 + c4;
    bf16x8 v0 = *(const bf16x8*)src;
    bf16x8 v1 = *(const bf16x8*)(src + 8);
#pragma unroll
    for (int j = 0; j < 8; ++j) tile[r][c4 + j] = v0[j];
#pragma unroll
    for (int j = 0; j < 8; ++j) tile[r][c4 + 8 + j] = v1[j];
    __syncthreads();
    int dd = t >> 2, kc = (t & 3) * 16;
    bf16_t* dst = vt + (long)z * (HEAD_DIM * SEQL) + (long)(d0 + dd) * SEQL + k0 + kc;
    bf16x8 o0, o1;
#pragma unroll
    for (int j = 0; j < 8; ++j) o0[j] = tile[kc + j][dd];
#pragma unroll
    for (int j = 0; j < 8; ++j) o1[j] = tile[kc + 8 + j][dd];
    *(bf16x8*)dst = o0;
    *(bf16x8*)(dst + 8) = o1;
}

// ---------------------------------------------------------------- softmax rows of S
__global__ void softmax_kernel(const float* __restrict__ S, bf16_t* __restrict__ P) {
    long row = blockIdx.x;  // 4096 = (b,h,q)
    int tid = threadIdx.x;  // 256
    float s = S[row * SEQL + tid] * 0.044194173824159216f;  // 1/sqrt(512)
    __shared__ float red[4];
    float m = warp_reduce_max(s);
    if ((tid & 63) == 0) red[tid >> 6] = m;
    __syncthreads();
    float gm = fmaxf(fmaxf(red[0], red[1]), fmaxf(red[2], red[3]));
    __syncthreads();
    float p = __expf(s - gm);
    float su = warp_reduce_sum(p);
    if ((tid & 63) == 0) red[tid >> 6] = su;
    __syncthreads();
    float gs = red[0] + red[1] + red[2] + red[3];
    P[row * SEQL + tid] = (bf16_t)(p / gs);
}

// ---------------------------------------------------------------- conv + silu + transpose
__global__ void conv_tr_kernel(const bf16_t* __restrict__ xzb, const float* __restrict__ cw,
                               const float* __restrict__ cb, bf16_t* __restrict__ xT,
                               bf16_t* __restrict__ xcb, bf16_t* __restrict__ zT) {
    __shared__ bf16_t xin[68][64];
    __shared__ bf16_t outt[64][72];  // [e_local][l_local]
    const int e0 = blockIdx.x * 64, l0 = blockIdx.y * 64, b = blockIdx.z;
    const int t = threadIdx.x;
    const int r = t >> 4;            // 0..15
    const int c = (t & 15) * 4;      // 0..60

#pragma unroll
    for (int i = 0; i < 5; ++i) {
        int m = r + i * 16;
        if (m < 67) {
            int l = l0 - 3 + m;
            bf16x4 v;
            if (l >= 0)
                v = *(const bf16x4*)(xzb + ((long)(b * SEQL + l)) * (2 * ED) + e0 + c);
            else {
                v[0] = (bf16_t)0.f; v[1] = (bf16_t)0.f; v[2] = (bf16_t)0.f; v[3] = (bf16_t)0.f;
            }
            *(bf16x4*)&xin[m][c] = v;
        }
    }
    __syncthreads();

    {
        const int e_l = t & 63;
        const int lbase = (t >> 6) * 16;
        const float4 wv = *(const float4*)(cw + (long)(e0 + e_l) * 4);
        const float bias = cb[e0 + e_l];
#pragma unroll
        for (int k = 0; k < 16; ++k) {
            int l = lbase + k;
            float acc = bias + wv.x * (float)xin[l][e_l] + wv.y * (float)xin[l + 1][e_l] +
                        wv.z * (float)xin[l + 2][e_l] + wv.w * (float)xin[l + 3][e_l];
            float s = acc / (1.f + __expf(-acc));
            outt[e_l][l] = (bf16_t)s;
        }
    }
    __syncthreads();

    {
        int er = t >> 2, lc = (t & 3) * 16;
        bf16x8 a = *(bf16x8*)&outt[er][lc];
        bf16x8 bb8 = *(bf16x8*)&outt[er][lc + 8];
        bf16_t* dst = xT + ((long)b * ED + e0 + er) * SEQL + l0 + lc;
        *(bf16x8*)dst = a;
        *(bf16x8*)(dst + 8) = bb8;
    }
    {
        int lr = t >> 2, ec = (t & 3) * 16;
        bf16_t tmp[16];
#pragma unroll
        for (int j = 0; j < 16; ++j) tmp[j] = outt[ec + j][lr];
        bf16_t* dst = xcb + ((long)(b * SEQL + l0 + lr)) * ED + e0 + ec;
        *(bf16x8*)dst = *(bf16x8*)&tmp[0];
        *(bf16x8*)(dst + 8) = *(bf16x8*)&tmp[8];
    }
    __syncthreads();

#pragma unroll
    for (int i = 0; i < 4; ++i) {
        int m = r + i * 16;
        bf16x4 v = *(const bf16x4*)(xzb + ((long)(b * SEQL + l0 + m)) * (2 * ED) + ED + e0 + c);
        *(bf16x4*)&xin[m][c] = v;
    }
    __syncthreads();
    {
        int er = t >> 2, lc = (t & 3) * 16;
        bf16_t tz[16];
#pragma unroll
        for (int j = 0; j < 16; ++j) tz[j] = xin[lc + j][er];
        bf16_t* dst = zT + ((long)b * ED + e0 + er) * SEQL + l0 + lc;
        *(bf16x8*)dst = *(bf16x8*)&tz[0];
        *(bf16x8*)(dst + 8) = *(bf16x8*)&tz[8];
    }
}

// ---------------------------------------------------------------- chunk-parallel selective scan
__global__ __launch_bounds__(256) void scan_chunk_kernel(
    const float* __restrict__ dT, const bf16_t* __restrict__ xT, const bf16_t* __restrict__ zT,
    const float* __restrict__ dbc, const float* __restrict__ A_log, const float* __restrict__ Dp,
    bf16_t* __restrict__ yT) {
    __shared__ float bc[SEQL][36];  // permuted rows; cols 0..15 = B, 16..31 = C
    const int t = threadIdx.x;
    const int chunk = t & 15;
    const int el = t >> 4;
    const int b = blockIdx.y;
    const int e = blockIdx.x * 16 + el;
    const int l0 = chunk * 16;
    const int R = DT_RANK + 2 * D_STATE;  // 160

    {
        const int row0 = t >> 3;
        const int col = (t & 7) * 4;
        const float* src = dbc + (long)b * SEQL * R + DT_RANK;
#pragma unroll
        for (int it = 0; it < 8; ++it) {
            int row = row0 + it * 32;
            int prow = ((row & 15) << 4) | (row >> 4);
            *(float4*)&bc[prow][col] = *(const float4*)(src + (long)row * R + col);
        }
    }

    float Ar[16];
    {
        const float* ap = A_log + (long)e * D_STATE;
#pragma unroll
        for (int n = 0; n < 16; n += 4) {
            float4 v = *(const float4*)(ap + n);
            Ar[n] = -__expf(v.x);
            Ar[n + 1] = -__expf(v.y);
            Ar[n + 2] = -__expf(v.z);
            Ar[n + 3] = -__expf(v.w);
        }
    }
    float d[16];
    {
        const float* dp = dT + ((long)b * ED + e) * SEQL + l0;
#pragma unroll
        for (int j = 0; j < 16; j += 4) *(float4*)&d[j] = *(const float4*)(dp + j);
    }
    float xf[16];
    {
        const bf16_t* xp = xT + ((long)b * ED + e) * SEQL + l0;
        bf16x8 x0 = *(const bf16x8*)xp;
        bf16x8 x1 = *(const bf16x8*)(xp + 8);
#pragma unroll
        for (int j = 0; j < 8; ++j) {
            xf[j] = (float)x0[j];
            xf[8 + j] = (float)x1[j];
        }
    }
    __syncthreads();

    float P[16], S[16];
#pragma unroll
    for (int n = 0; n < 16; ++n) {
        P[n] = 1.f;
        S[n] = 0.f;
    }

#pragma unroll
    for (int j = 0; j < 16; ++j) {
        const float* br = &bc[(j << 4) | chunk][0];
        float dj = d[j];
        float dx = dj * xf[j];
#pragma unroll
        for (int n = 0; n < 16; ++n) {
            float dA = __expf(dj * Ar[n]);
            S[n] = dA * S[n] + dx * br[n];
            P[n] *= dA;
        }
    }

#pragma unroll
    for (int off = 1; off < 16; off <<= 1) {
        float Pp[16], Sp[16];
#pragma unroll
        for (int n = 0; n < 16; ++n) {
            Pp[n] = __shfl_up(P[n], off, 16);
            Sp[n] = __shfl_up(S[n], off, 16);
        }
        if (chunk >= off) {
#pragma unroll
            for (int n = 0; n < 16; ++n) {
                S[n] = P[n] * Sp[n] + S[n];
                P[n] *= Pp[n];
            }
        }
    }

    float h[16];
#pragma unroll
    for (int n = 0; n < 16; ++n) {
        float hs = __shfl_up(S[n], 1, 16);
        h[n] = (chunk == 0) ? 0.f : hs;
    }

    const float dpe = Dp[e];
    float yf[16];
#pragma unroll
    for (int j = 0; j < 16; ++j) {
        const float* br = &bc[(j << 4) | chunk][0];
        float dj = d[j];
        float dx = dj * xf[j];
        float y = 0.f;
#pragma unroll
        for (int n = 0; n < 16; ++n) {
            float dA = __expf(dj * Ar[n]);
            h[n] = dA * h[n] + dx * br[n];
            y += h[n] * br[16 + n];
        }
        yf[j] = y + xf[j] * dpe;
    }

    const bf16_t* zp = zT + ((long)b * ED + e) * SEQL + l0;
    bf16_t* yp = yT + ((long)b * ED + e) * SEQL + l0;
    {
        bf16x8 z0 = *(const bf16x8*)zp;
        bf16x8 o0;
#pragma unroll
        for (int j = 0; j < 8; ++j) {
            float z = (float)z0[j];
            o0[j] = (bf16_t)(yf[j] * (z / (1.f + __expf(-z))));
        }
        *(bf16x8*)yp = o0;
        bf16x8 z1 = *(const bf16x8*)(zp + 8);
        bf16x8 o1;
#pragma unroll
        for (int j = 0; j < 8; ++j) {
            float z = (float)z1[j];
            o1[j] = (bf16_t)(yf[8 + j] * (z / (1.f + __expf(-z))));
        }
        *(bf16x8*)(yp + 8) = o1;
    }
}

// ---------------------------------------------------------------- yT [B][ED][L] -> Y [B*L][ED]
__global__ void ytr_kernel(const bf16_t* __restrict__ yT, bf16_t* __restrict__ Y) {
    __shared__ bf16_t tl[64][72];
    const int e0 = blockIdx.x * 64, l0 = blockIdx.y * 64, b = blockIdx.z;
    const int t = threadIdx.x;
    {
        int er = t >> 2, lc = (t & 3) * 16;
        const bf16_t* src = yT + ((long)b * ED + e0 + er) * SEQL + l0 + lc;
        bf16x8 a = *(const bf16x8*)src;
        bf16x8 bb8 = *(const bf16x8*)(src + 8);
        *(bf16x8*)&tl[er][lc] = a;
        *(bf16x8*)&tl[er][lc + 8] = bb8;
    }
    __syncthreads();
    {
        int lr = t >> 2, ec = (t & 3) * 16;
        bf16_t tmp[16];
#pragma unroll
        for (int j = 0; j < 16; ++j) tmp[j] = tl[ec + j][lr];
        bf16_t* dst = Y + ((long)(b * SEQL + l0 + lr)) * ED + e0 + ec;
        *(bf16x8*)dst = *(bf16x8*)&tmp[0];
        *(bf16x8*)(dst + 8) = *(bf16x8*)&tmp[8];
    }
}

// ---------------------------------------------------------------- head GEMV1
__global__ void head_gemv1(const float* __restrict__ H, const float* __restrict__ w1,
                           const float* __restrict__ b1, float* __restrict__ hm1) {
    int b = blockIdx.y;
    int wave = threadIdx.x >> 6, lane = threadIdx.x & 63;
    int n = blockIdx.x * 4 + wave;
    const float* last = H + ((long)(b * SEQL + SEQL - 1)) * D_MODEL;
    const float* wr = w1 + (long)n * D_MODEL;
    float s = 0.f;
    for (int j = lane * 4; j < D_MODEL; j += 256) {
        float4 a = *(const float4*)(last + j);
        float4 w = *(const float4*)(wr + j);
        s += a.x * w.x + a.y * w.y + a.z * w.z + a.w * w.w;
    }
    s = warp_reduce_sum(s);
    if (lane == 0) hm1[b * 1024 + n] = s + b1[n];
}

// ---------------------------------------------------------------- head final
__global__ void head_final(const float* __restrict__ hm1, const float* __restrict__ ln_g,
                           const float* __restrict__ ln_b, const float* __restrict__ w2,
                           const float* __restrict__ b2, float* __restrict__ out) {
    int b = blockIdx.x;
    int tid = threadIdx.x;  // 1024
    __shared__ float hm[1024];
    __shared__ float r1[16], r2[16];
    __shared__ float stats[2];
    __shared__ float outs[64];

    float v = hm1[b * 1024 + tid];
    float s1 = warp_reduce_sum(v);
    float s2 = warp_reduce_sum(v * v);
    int wave = tid >> 6;
    if ((tid & 63) == 0) { r1[wave] = s1; r2[wave] = s2; }
    __syncthreads();
    if (tid == 0) {
        float t1 = 0.f, t2 = 0.f;
        for (int w = 0; w < 16; ++w) { t1 += r1[w]; t2 += r2[w]; }
        float mean = t1 / 1024.f;
        stats[0] = mean;
        stats[1] = rsqrtf(t2 / 1024.f - mean * mean + 1e-5f);
    }
    __syncthreads();
    float x = (v - stats[0]) * stats[1] * ln_g[tid] + ln_b[tid];
    x = (x > 0.f) ? x : (__expf(x) - 1.f);
    hm[tid] = x;
    __syncthreads();

    int o = tid >> 4, kk = tid & 15;
    float a = 0.f;
    const float* w2r = w2 + (long)o * 1024;
    for (int j = kk; j < 1024; j += 16) a += hm[j] * w2r[j];
#pragma unroll
    for (int off = 1; off < 16; off <<= 1) a += __shfl_xor(a, off);
    if (kk == 0) outs[o] = a + b2[o];
    __syncthreads();
    if (tid < 64) {
        float vv = outs[tid];
        float ss = warp_reduce_sum(vv * vv);
        out[b * 64 + tid] = vv / fmaxf(sqrtf(ss), 1e-12f);
    }
}

// ---------------------------------------------------------------- launch
extern "C" void kernel_launch(void* const* d_in, const int* in_sizes, int n_in,
                              void* d_out, int out_size, void* d_ws, size_t ws_size,
                              hipStream_t stream) {
    const float* x = (const float*)d_in[0];
    const float* norm_w = (const float*)d_in[1];
    const float* in_proj_w = (const float*)d_in[2];
    const float* conv_w = (const float*)d_in[3];
    const float* conv_b = (const float*)d_in[4];
    const float* x_proj_w = (const float*)d_in[5];
    const float* dt_proj_w = (const float*)d_in[6];
    const float* dt_proj_b = (const float*)d_in[7];
    const float* A_log = (const float*)d_in[8];
    const float* D_param = (const float*)d_in[9];
    const float* out_proj_w = (const float*)d_in[10];
    const float* attn_in_w = (const float*)d_in[11];
    const float* attn_in_b = (const float*)d_in[12];
    const float* attn_out_w = (const float*)d_in[13];
    const float* attn_out_b = (const float*)d_in[14];
    const float* w1 = (const float*)d_in[15];
    const float* b1 = (const float*)d_in[16];
    const float* ln_g = (const float*)d_in[17];
    const float* ln_b = (const float*)d_in[18];
    const float* w2 = (const float*)d_in[19];
    const float* b2 = (const float*)d_in[20];

    float* ws = (float*)d_ws;
    // ---- workspace layout (floats) — identical to round 9
    float* H = ws;                                    // @0        2097152
    float* SCR = ws + 2097152;                        // @2097152  6291456
    bf16_t* XNb = (bf16_t*)(ws + 8388608);            // @8388608  1048576
    float* DELTA_unused = ws + 9437184;               // @9437184  4194304 (now scratch for WBin)
    float* DBC = ws + 13631488;                       // @13631488 163840
    float* XPART = ws + 13795328;                     // @13795328 1310720
    bf16_t* XCb = (bf16_t*)(ws + 15106048);           // @15106048 2097152
    bf16_t* DTb = (bf16_t*)(ws + 17203200);           // @17203200 65536
    bf16_t* Yb = (bf16_t*)(ws + 17268736);            // @17268736 2097152
    bf16_t* Hb = (bf16_t*)(ws + 19365888);            // @19365888 1048576
    bf16_t* AOb = (bf16_t*)(ws + 20414464);           // @20414464 1048576
    float* HM1 = ws + 21463040;                       // @21463040 4096
    bf16_t* XT = (bf16_t*)(ws + 21467136);            // @21467136 2097152
    bf16_t* ZT = (bf16_t*)(ws + 23564288);            // @23564288 2097152
    (void)DELTA_unused;

    // weight bf16 staging buffers (dead-at-time regions, audited round 9):
    bf16_t* WBin = (bf16_t*)(ws + 9437184);   // in_proj 16.8M elem (DELTA..Yb-head, Yb dead then)
    bf16_t* WBout = (bf16_t*)(ws + 21467136); // out_proj 8.4M elem = XT+ZT (dead post-scan)
    bf16_t* WBai = (bf16_t*)(ws + 8388608);   // attn_in 12.6M elem (XNb..XPART, dead in attn)
    bf16_t* WBao = (bf16_t*)(ws + 21467136);  // attn_out 4.2M elem = XT (dead in attn)

    bf16_t* XZb = (bf16_t*)SCR;                       // [B*L][2ED] bf16 (dead after conv_tr)
    float* DTT = SCR;                                 // [B][ED][L] f32 (after XZb dead)
    bf16_t* YTT = (bf16_t*)(SCR + 4194304);           // [B][ED][L] bf16
    float* PART = SCR;                                // splitK partials (8.4M floats ok)

    bf16_t* QKVb = (bf16_t*)SCR;                      // attention phase
    float* SBUF = SCR + 3145728;
    bf16_t* Pb = (bf16_t*)(SCR + 3145728 + 1048576);
    bf16_t* VTb = (bf16_t*)(SCR + 3145728 + 1048576 + 524288);

    const int M = BATCH * SEQL;  // 1024
    const long S_H = (long)M * D_MODEL;

    copy4_kernel<<<2048, 256, 0, stream>>>((const float4*)x, (float4*)H, (int)(S_H / 4));

    for (int i = 0; i < N_LAYERS; ++i) {
        rmsnorm_kernel<<<M, 256, 0, stream>>>(H, norm_w + (long)i * D_MODEL, XNb);
        // in_proj: bf16 weights + 64x128-tile GEMM (1024 blocks)
        f2b8_kernel<<<8192, 256, 0, stream>>>(in_proj_w + (long)i * 2 * ED * D_MODEL, WBin,
                                              (long)2 * ED * D_MODEL / 8);
        gemm_w64<<<dim3(64, 16, 1), 256, 0, stream>>>(XNb, D_MODEL, WBin, D_MODEL, XZb, 2 * ED,
                                                      D_MODEL, nullptr, 1, 0);
        conv_tr_kernel<<<dim3(64, 4, 4), 256, 0, stream>>>(
            XZb, conv_w + (long)i * ED * D_CONV, conv_b + (long)i * ED, XT, XCb, ZT);
        // x_proj split-K=8 -> XPART; ksum fused with dt-pack
        gemm_bf16<<<dim3(2, 8, 8), 256, 0, stream>>>(
            XCb, ED, x_proj_w + (long)i * (DT_RANK + 2 * D_STATE) * ED, ED, XPART,
            DT_RANK + 2 * D_STATE, DT_RANK + 2 * D_STATE, ED / 8, nullptr, 0,
            (long)M * (DT_RANK + 2 * D_STATE));
        ksum_dt_kernel<<<640, 256, 0, stream>>>(XPART, DBC, DTb, M * (DT_RANK + 2 * D_STATE), 8,
                                                (long)M * (DT_RANK + 2 * D_STATE));
        // dt_proj with fused softplus+bias+transpose epilogue -> DTT[b][e][l]
        gemm_bf16<<<dim3(32, 8, 1), 256, 0, stream>>>(
            DTb, DT_RANK, dt_proj_w + (long)i * ED * DT_RANK, DT_RANK, DTT, 0, ED, DT_RANK,
            dt_proj_b + (long)i * ED, 2, 0);
        scan_chunk_kernel<<<dim3(ED / 16, BATCH), 256, 0, stream>>>(
            DTT, XT, ZT, DBC, A_log + (long)i * ED * D_STATE, D_param + (long)i * ED, YTT);
        ytr_kernel<<<dim3(64, 4, 4), 256, 0, stream>>>(YTT, Yb);
        // out_proj: bf16 weights into XT/ZT (dead post-scan), split-K=4 -> PART, add into H
        f2b8_kernel<<<4096, 256, 0, stream>>>(out_proj_w + (long)i * D_MODEL * ED, WBout,
                                              (long)D_MODEL * ED / 8);
        gemm_w64<<<dim3(16, 16, 4), 256, 0, stream>>>(Yb, ED, WBout, ED, PART, D_MODEL, ED / 4,
                                                      nullptr, 0, (long)M * D_MODEL);
        ksum_add_kernel<<<8192, 256, 0, stream>>>(PART, H, M * D_MODEL, 4, (long)M * D_MODEL,
                                                  nullptr, 0);
    }

    f2b8_kernel<<<1024, 256, 0, stream>>>(H, Hb, S_H / 8);
    f2b8_kernel<<<6144, 256, 0, stream>>>(attn_in_w, WBai, (long)3 * D_MODEL * D_MODEL / 8);
    gemm_w64<<<dim3(48, 16, 1), 256, 0, stream>>>(Hb, D_MODEL, WBai, D_MODEL, QKVb, 3 * D_MODEL,
                                                  D_MODEL, attn_in_b, 1, 0);
    vtrans_kernel<<<dim3(8, 4, 16), 256, 0, stream>>>(QKVb, VTb);
    // scores: S[z][q][k] = Q·K^T (batched, BM=64 -> 128 blocks)
    gemm_bb64<<<dim3(2, 4, 16), 256, 0, stream>>>(
        QKVb, (long)SEQL * 3 * D_MODEL, HEAD_DIM, 3 * D_MODEL,
        QKVb + D_MODEL, (long)SEQL * 3 * D_MODEL, HEAD_DIM, 3 * D_MODEL,
        SBUF, 4L * SEQL * SEQL, (long)SEQL * SEQL, SEQL, HEAD_DIM, 0);
    softmax_kernel<<<BATCH * N_HEADS * SEQL, 256, 0, stream>>>(SBUF, Pb);
    // AO = P·VT^T (batched, BM=64 -> 256 blocks), bf16 out strided into AOb
    gemm_bb64<<<dim3(4, 4, 16), 256, 0, stream>>>(
        Pb, 4L * SEQL * SEQL, (long)SEQL * SEQL, SEQL,
        VTb, 4L * HEAD_DIM * SEQL, (long)HEAD_DIM * SEQL, SEQL,
        AOb, (long)SEQL * D_MODEL, HEAD_DIM, D_MODEL, SEQL, 1);
    // attn_out: bf16 weights into XT (dead), split-K=4; bias folded into the reduce
    f2b8_kernel<<<2048, 256, 0, stream>>>(attn_out_w, WBao, (long)D_MODEL * D_MODEL / 8);
    gemm_w64<<<dim3(16, 16, 4), 256, 0, stream>>>(AOb, D_MODEL, WBao, D_MODEL, PART, D_MODEL,
                                                  D_MODEL / 4, nullptr, 0, (long)M * D_MODEL);
    ksum_add_kernel<<<8192, 256, 0, stream>>>(PART, H, M * D_MODEL, 4, (long)M * D_MODEL,
                                              attn_out_b, D_MODEL - 1);

    head_gemv1<<<dim3(256, 4), 256, 0, stream>>>(H, w1, b1, HM1);
    head_final<<<BATCH, 1024, 0, stream>>>(HM1, ln_g, ln_b, w2, b2, (float*)d_out);
}